// Round 5
// baseline (171.548 us; speedup 1.0000x reference)
//
#include <hip/hip_runtime.h>
#include <cstdint>
#include <cstddef>

#define BB 4
#define HCC 32
#define WCC 32
#define KCC 1024
#define NCC (HCC*WCC)
#define HFF 128
#define WFF 128
#define KFF 256
#define DCC 4
#define NCHUNK 8

typedef _Float16 half8 __attribute__((ext_vector_type(8)));
typedef _Float16 half4_t __attribute__((ext_vector_type(4)));
typedef float f32x4 __attribute__((ext_vector_type(4)));
#define MFMA16(a,b,c) __builtin_amdgcn_mfma_f32_16x16x32_f16((a),(b),(c),0,0,0)
#define INV2K 0.00048828125f

// split fp32 -> (hi fp16, lo' = fp16(2048*(x-hi))).  dot = S1 + S2/2048.
__device__ inline void cvt8(const float4 u0, const float4 u1, half8& h, half8& l2) {
  float uu[8];
  *(float4*)uu = u0; *(float4*)(uu + 4) = u1;
  #pragma unroll
  for (int e = 0; e < 8; ++e) {
    _Float16 hh = (_Float16)uu[e];
    float r = (uu[e] - (float)hh) * 2048.0f;
    h[e] = hh; l2[e] = (_Float16)r;
  }
}

// ======== pre-convert (coarse): fp32 rows -> separate hi/lo planes + norms ========
template<int K>
__global__ __launch_bounds__(256) void preconv_kernel(
    const float* __restrict__ src0, const float* __restrict__ src1,
    _Float16* __restrict__ hi0, _Float16* __restrict__ lo0,
    _Float16* __restrict__ hi1, _Float16* __restrict__ lo1,
    float* __restrict__ nr0, float* __restrict__ nr1, int rows) {
  const float* __restrict__ src = blockIdx.y ? src1 : src0;
  _Float16* __restrict__ hi = blockIdx.y ? hi1 : hi0;
  _Float16* __restrict__ lo = blockIdx.y ? lo1 : lo0;
  float* __restrict__ nrm = blockIdx.y ? nr1 : nr0;
  const int wave = threadIdx.x >> 6, lane = threadIdx.x & 63;
  const int row = blockIdx.x * 4 + wave;
  if (row >= rows) return;
  const float* p = src + (size_t)row * K;
  const size_t ob = (size_t)row * K + lane * 4;
  float s = 0.f;
  #pragma unroll
  for (int c = 0; c < K / 256; ++c) {
    float4 v = *(const float4*)(p + c * 256 + lane * 4);
    s += v.x*v.x + v.y*v.y + v.z*v.z + v.w*v.w;
    float vv[4] = {v.x, v.y, v.z, v.w};
    half4_t h, l2;
    #pragma unroll
    for (int e = 0; e < 4; ++e) {
      _Float16 hh = (_Float16)vv[e];
      l2[e] = (_Float16)((vv[e] - (float)hh) * 2048.0f);
      h[e] = hh;
    }
    *(half4_t*)(hi + ob + c * 256) = h;
    *(half4_t*)(lo + ob + c * 256) = l2;
  }
  #pragma unroll
  for (int m = 1; m <= 32; m <<= 1) s += __shfl_xor(s, m, 64);
  if (lane == 0) nrm[row] = s;
}

// ======== pre-convert (fine): fp32 rows (K=256) -> interleaved [hi8|lo8] + norms ====
// layout per row: 512 halfs, chunk s (0..7): [s*64 .. s*64+63] = q=0..3 x {hi8, lo8}
__global__ __launch_bounds__(256) void preconv_fine_kernel(
    const float* __restrict__ src, _Float16* __restrict__ hl,
    float* __restrict__ nrm, int rows) {
  const int wave = threadIdx.x >> 6, lane = threadIdx.x & 63;
  const int row = blockIdx.x * 4 + wave;
  if (row >= rows) return;
  float4 v = *(const float4*)(src + (size_t)row * KFF + lane * 4);
  float s = v.x*v.x + v.y*v.y + v.z*v.z + v.w*v.w;
  float vv[4] = {v.x, v.y, v.z, v.w};
  half4_t h, l2;
  #pragma unroll
  for (int e = 0; e < 4; ++e) {
    _Float16 hh = (_Float16)vv[e];
    l2[e] = (_Float16)((vv[e] - (float)hh) * 2048.0f);
    h[e] = hh;
  }
  const size_t dst = (size_t)row * 512 + (lane >> 3) * 64 + ((lane >> 1) & 3) * 16 + (lane & 1) * 4;
  *(half4_t*)(hl + dst)     = h;
  *(half4_t*)(hl + dst + 8) = l2;
  #pragma unroll
  for (int m = 1; m <= 32; m <<= 1) s += __shfl_xor(s, m, 64);
  if (lane == 0) nrm[row] = s;
}

// ======== coarse v2: plane inputs, 128 cands x 64 queries, fp16x3 MFMA ========
__global__ __launch_bounds__(256, 2) void coarse_kernel2(
    const _Float16* __restrict__ gAhi, const _Float16* __restrict__ gAlo,
    const _Float16* __restrict__ gBhi, const _Float16* __restrict__ gBlo,
    const float* __restrict__ na, const float* __restrict__ nq,
    float* __restrict__ pval, int* __restrict__ pidx) {
  __shared__ _Float16 Ahi[128][64], Alo[128][64];
  __shared__ _Float16 Bhi[64][64],  Blo[64][64];
  __shared__ float a2s[128], q2s[64];
  __shared__ float redv[2][64];
  __shared__ int   redi[2][64];

  const int t = threadIdx.x;
  const int chunk = blockIdx.x;
  const int n0 = blockIdx.y * 64;
  const int b  = blockIdx.z;
  const int m0 = chunk * 128;

  const int ar = t >> 1, ahf = t & 1;
  const int brw = t >> 2, bq = t & 3;
  const int l  = t & 63;
  const int wv = t >> 6;
  const int wm = wv >> 1, wn = wv & 1;

  if (t < 128) a2s[t] = na[b*NCC + m0 + t];
  else if (t < 192) q2s[t - 128] = nq[b*NCC + n0 + (t - 128)];

  const _Float16* __restrict__ gah = gAhi + (size_t)(b*NCC + m0 + ar) * KCC + ahf * 32;
  const _Float16* __restrict__ gal = gAlo + (size_t)(b*NCC + m0 + ar) * KCC + ahf * 32;
  const _Float16* __restrict__ gbh = gBhi + (size_t)(b*NCC + n0 + brw) * KCC + bq * 16;
  const _Float16* __restrict__ gbl = gBlo + (size_t)(b*NCC + n0 + brw) * KCC + bq * 16;

  f32x4 accA[4][2], accB[4][2];
  #pragma unroll
  for (int mt = 0; mt < 4; ++mt)
    #pragma unroll
    for (int nt = 0; nt < 2; ++nt) { accA[mt][nt] = (f32x4)0.f; accB[mt][nt] = (f32x4)0.f; }

  for (int k0 = 0; k0 < KCC; k0 += 64) {
    __syncthreads();
    #pragma unroll
    for (int c2 = 0; c2 < 4; ++c2) {
      half8 h  = *(const half8*)(gah + k0 + c2 * 8);
      half8 l8 = *(const half8*)(gal + k0 + c2 * 8);
      int cs = (ahf * 4 + c2) ^ (ar & 7);
      *(half8*)&Ahi[ar][cs * 8] = h;
      *(half8*)&Alo[ar][cs * 8] = l8;
    }
    #pragma unroll
    for (int c2 = 0; c2 < 2; ++c2) {
      half8 h  = *(const half8*)(gbh + k0 + c2 * 8);
      half8 l8 = *(const half8*)(gbl + k0 + c2 * 8);
      int cs = (bq * 2 + c2) ^ (brw & 7);
      *(half8*)&Bhi[brw][cs * 8] = h;
      *(half8*)&Blo[brw][cs * 8] = l8;
    }
    __syncthreads();

    #pragma unroll
    for (int kk = 0; kk < 2; ++kk) {
      const int cs = ((kk * 4 + (l >> 4)) ^ (l & 7)) * 8;
      half8 ah[4], al[4], bh[2], bl[2];
      #pragma unroll
      for (int mt = 0; mt < 4; ++mt) {
        int row = wm * 64 + mt * 16 + (l & 15);
        ah[mt] = *(const half8*)&Ahi[row][cs];
        al[mt] = *(const half8*)&Alo[row][cs];
      }
      #pragma unroll
      for (int nt = 0; nt < 2; ++nt) {
        int row = wn * 32 + nt * 16 + (l & 15);
        bh[nt] = *(const half8*)&Bhi[row][cs];
        bl[nt] = *(const half8*)&Blo[row][cs];
      }
      #pragma unroll
      for (int mt = 0; mt < 4; ++mt)
        #pragma unroll
        for (int nt = 0; nt < 2; ++nt) {
          accA[mt][nt] = MFMA16(ah[mt], bh[nt], accA[mt][nt]);
          accB[mt][nt] = MFMA16(ah[mt], bl[nt], accB[mt][nt]);
          accB[mt][nt] = MFMA16(al[mt], bh[nt], accB[mt][nt]);
        }
    }
  }

  #pragma unroll
  for (int nt = 0; nt < 2; ++nt) {
    float q2 = q2s[wn * 32 + nt * 16 + (l & 15)];
    float bv = 3.0e38f; int bi = 0;
    #pragma unroll
    for (int mt = 0; mt < 4; ++mt)
      #pragma unroll
      for (int r = 0; r < 4; ++r) {
        float dot = accA[mt][nt][r] + accB[mt][nt][r] * INV2K;
        int ml = wm * 64 + mt * 16 + (l >> 4) * 4 + r;
        float d = (q2 + a2s[ml]) - 2.0f * dot;
        if (d < bv) { bv = d; bi = m0 + ml; }
      }
    #pragma unroll
    for (int mm = 16; mm < 64; mm <<= 1) {
      float ov = __shfl_xor(bv, mm, 64);
      int oi = __shfl_xor(bi, mm, 64);
      if (ov < bv || (ov == bv && oi < bi)) { bv = ov; bi = oi; }
    }
    if ((l >> 4) == 0) { redv[wm][wn*32 + nt*16 + l] = bv; redi[wm][wn*32 + nt*16 + l] = bi; }
  }
  __syncthreads();
  if (t < 64) {
    float v0 = redv[0][t]; int i0 = redi[0][t];
    float v1 = redv[1][t]; int i1 = redi[1][t];
    if (v1 < v0) { v0 = v1; i0 = i1; }
    pval[((size_t)b * NCC + n0 + t) * NCHUNK + chunk] = v0;
    pidx[((size_t)b * NCC + n0 + t) * NCHUNK + chunk] = i0;
  }
}

// ======== coarse: combine chunk partials ========
__global__ __launch_bounds__(256) void coarse_reduce_kernel(
    const float* __restrict__ pval, const int* __restrict__ pidx,
    int* __restrict__ out) {
  int g = blockIdx.x * 256 + threadIdx.x;
  if (g >= BB * NCC) return;
  float bv = pval[(size_t)g * NCHUNK];
  int bi = pidx[(size_t)g * NCHUNK];
  #pragma unroll
  for (int c = 1; c < NCHUNK; ++c) {
    float v = pval[(size_t)g * NCHUNK + c];
    int ix = pidx[(size_t)g * NCHUNK + c];
    if (v < bv) { bv = v; bi = ix; }
  }
  out[(size_t)g*2]     = bi >> 5;
  out[(size_t)g*2 + 1] = bi & 31;
}

// ======== fine v3: 9 waves/block, one 16-cand tile per wave, interleaved HL ========
__global__ __launch_bounds__(576, 4) void fine_kernel3(
    const _Float16* __restrict__ gHL,
    const float* __restrict__ fkf, const float* __restrict__ naf,
    const int* __restrict__ coarse, int* __restrict__ outf) {
  __shared__ _Float16 Qhi[16][256], Qlo[16][256];
  __shared__ float qn[16];
  __shared__ int cbr[9], cbc[9];
  __shared__ float redv[9][16];
  __shared__ int   redi[9][16];

  const int t = threadIdx.x;
  const int bx = blockIdx.x, i = blockIdx.y, b = blockIdx.z;
  // chunked swizzle: 4 consecutive j per XCD, strips rotated per batch
  const int j = (((bx & 7) + b) & 7) * 4 + (bx >> 3);
  const int l = t & 63, wv = t >> 6;

  if (t < 9) {
    int di = t / 3 - 1, dj = t % 3 - 1;
    int y = min(max(i + di, 0), HCC - 1);
    int x = min(max(j + dj, 0), WCC - 1);
    int base = ((b*HCC + y)*WCC + x) * 2;
    cbr[t] = coarse[base];
    cbc[t] = coarse[base + 1];
  }
  __syncthreads();

  // this wave's candidate tile = wv; lane row = l&15, k-quarter = l>>4
  const int srow = l & 15;
  const int rr = cbr[wv]*DCC + (srow >> 2), cc = cbc[wv]*DCC + (srow & 3);
  const _Float16* ap = gHL + ((size_t)((b*HFF + rr)*WFF + cc)) * 512 + (l >> 4) * 16;

  // prefetch steps 0 and 1 (in flight across the Q-staging barrier)
  half8 h0 = *(const half8*)(ap +  0);
  half8 l0 = *(const half8*)(ap +  8);
  half8 h1 = *(const half8*)(ap + 64);
  half8 l1 = *(const half8*)(ap + 72);

  // wave 0 stages queries (fp32 -> hi/lo planes) + query norms
  if (t < 64) {
    int qr = l & 15, qq = l >> 4;
    int fr = i*DCC + (qr >> 2), fc = j*DCC + (qr & 3);
    const float* src = fkf + ((size_t)(b*HFF + fr)*WFF + fc) * KFF + qq * 64;
    float s2 = 0.f;
    #pragma unroll
    for (int c2 = 0; c2 < 8; ++c2) {
      float4 u0 = *(const float4*)(src + c2*8);
      float4 u1 = *(const float4*)(src + c2*8 + 4);
      s2 += u0.x*u0.x + u0.y*u0.y + u0.z*u0.z + u0.w*u0.w
          + u1.x*u1.x + u1.y*u1.y + u1.z*u1.z + u1.w*u1.w;
      half8 hh, hl;
      cvt8(u0, u1, hh, hl);
      int cs = (qq * 8 + c2) ^ (qr & 7);
      *(half8*)&Qhi[qr][cs * 8] = hh;
      *(half8*)&Qlo[qr][cs * 8] = hl;
    }
    s2 += __shfl_xor(s2, 16, 64);
    s2 += __shfl_xor(s2, 32, 64);
    if (qq == 0) qn[qr] = s2;
  }
  __syncthreads();

  f32x4 accA = (f32x4)0.f, accB = (f32x4)0.f;
  #pragma unroll
  for (int s = 0; s < 8; ++s) {
    half8 nh, nl;
    if (s < 6) {
      nh = *(const half8*)(ap + (s + 2) * 64);
      nl = *(const half8*)(ap + (s + 2) * 64 + 8);
    }
    const int cs = ((s * 4 + (l >> 4)) ^ (l & 7)) * 8;
    half8 bh = *(const half8*)&Qhi[l & 15][cs];
    half8 bl = *(const half8*)&Qlo[l & 15][cs];
    accA = MFMA16(h0, bh, accA);
    accB = MFMA16(h0, bl, accB);
    accB = MFMA16(l0, bh, accB);
    h0 = h1; l0 = l1;
    if (s < 6) { h1 = nh; l1 = nl; }
  }

  // epilogue: dist + argmin (first-index ties); cand norms gathered from naf
  {
    float q2 = qn[l & 15];
    float bv = 3.0e38f; int bi = 0;
    #pragma unroll
    for (int r = 0; r < 4; ++r) {
      int s4 = (l >> 4) * 4 + r;
      int r2 = cbr[wv]*DCC + (s4 >> 2), c2 = cbc[wv]*DCC + (s4 & 3);
      float c2n = naf[(b*HFF + r2)*WFF + c2];
      float dot = accA[r] + accB[r] * INV2K;
      float d = (q2 + c2n) - 2.0f * dot;
      int m = wv * 16 + s4;
      if (d < bv) { bv = d; bi = m; }
    }
    #pragma unroll
    for (int mm = 16; mm < 64; mm <<= 1) {
      float ov = __shfl_xor(bv, mm, 64);
      int oi = __shfl_xor(bi, mm, 64);
      if (ov < bv || (ov == bv && oi < bi)) { bv = ov; bi = oi; }
    }
    if (l < 16) { redv[wv][l] = bv; redi[wv][l] = bi; }
  }
  __syncthreads();

  if (t < 16) {
    float v = redv[0][t]; int ix = redi[0][t];
    #pragma unroll
    for (int w = 1; w < 9; ++w) {
      float ov = redv[w][t];
      if (ov < v) { v = ov; ix = redi[w][t]; }   // wave idx ranges ascending
    }
    int n9 = ix >> 4, s3 = ix & 15;
    int br = cbr[n9]*DCC + (s3 >> 2);
    int bc = cbc[n9]*DCC + (s3 & 3);
    int fr = i*DCC + (t >> 2), fc = j*DCC + (t & 3);
    size_t ob = ((size_t)(b*HFF + fr)*WFF + fc) * 2;
    outf[ob]     = br;
    outf[ob + 1] = bc;
  }
}

// ================== R3 fallback path (used if ws too small) ==================
__global__ __launch_bounds__(256, 2) void coarse_kernel(
    const float* __restrict__ f1, const float* __restrict__ fk,
    float* __restrict__ pval, int* __restrict__ pidx) {
  __shared__ _Float16 Ahi[128][64], Alo[128][64];
  __shared__ _Float16 Bhi[64][64],  Blo[64][64];
  __shared__ float npA[256], npB[256];
  __shared__ float a2s[128], q2s[64];
  __shared__ float redv[2][64];
  __shared__ int   redi[2][64];

  const int t = threadIdx.x;
  const int chunk = blockIdx.x;
  const int n0 = blockIdx.y * 64;
  const int b  = blockIdx.z;
  const int m0 = chunk * 128;

  const float* __restrict__ Abase = f1 + ((size_t)b * NCC + m0) * KCC;
  const float* __restrict__ Bbase = fk + ((size_t)b * NCC + n0) * KCC;

  const int ar = t >> 1, ahf = t & 1;
  const int brw = t >> 2, bq = t & 3;
  const int l  = t & 63;
  const int wv = t >> 6;
  const int wm = wv >> 1, wn = wv & 1;

  float nrmA = 0.f, nrmB = 0.f;
  f32x4 accA[4][2], accB[4][2];
  #pragma unroll
  for (int mt = 0; mt < 4; ++mt)
    #pragma unroll
    for (int nt = 0; nt < 2; ++nt) { accA[mt][nt] = (f32x4)0.f; accB[mt][nt] = (f32x4)0.f; }

  for (int k0 = 0; k0 < KCC; k0 += 64) {
    __syncthreads();
    {
      const float4* src = (const float4*)(Abase + (size_t)ar * KCC + k0 + ahf * 32);
      float4 va[8];
      #pragma unroll
      for (int i2 = 0; i2 < 8; ++i2) va[i2] = src[i2];
      #pragma unroll
      for (int i2 = 0; i2 < 8; ++i2)
        nrmA += va[i2].x*va[i2].x + va[i2].y*va[i2].y + va[i2].z*va[i2].z + va[i2].w*va[i2].w;
      #pragma unroll
      for (int c2 = 0; c2 < 4; ++c2) {
        half8 hh, hl;
        cvt8(va[c2*2], va[c2*2+1], hh, hl);
        int cs = (ahf * 4 + c2) ^ (ar & 7);
        *(half8*)&Ahi[ar][cs * 8] = hh;
        *(half8*)&Alo[ar][cs * 8] = hl;
      }
    }
    {
      const float4* src = (const float4*)(Bbase + (size_t)brw * KCC + k0 + bq * 16);
      float4 vb[4];
      #pragma unroll
      for (int i2 = 0; i2 < 4; ++i2) vb[i2] = src[i2];
      #pragma unroll
      for (int i2 = 0; i2 < 4; ++i2)
        nrmB += vb[i2].x*vb[i2].x + vb[i2].y*vb[i2].y + vb[i2].z*vb[i2].z + vb[i2].w*vb[i2].w;
      #pragma unroll
      for (int c2 = 0; c2 < 2; ++c2) {
        half8 hh, hl;
        cvt8(vb[c2*2], vb[c2*2+1], hh, hl);
        int cs = (bq * 2 + c2) ^ (brw & 7);
        *(half8*)&Bhi[brw][cs * 8] = hh;
        *(half8*)&Blo[brw][cs * 8] = hl;
      }
    }
    __syncthreads();

    #pragma unroll
    for (int kk = 0; kk < 2; ++kk) {
      const int cs = ((kk * 4 + (l >> 4)) ^ (l & 7)) * 8;
      half8 ah[4], al[4], bh[2], bl[2];
      #pragma unroll
      for (int mt = 0; mt < 4; ++mt) {
        int row = wm * 64 + mt * 16 + (l & 15);
        ah[mt] = *(const half8*)&Ahi[row][cs];
        al[mt] = *(const half8*)&Alo[row][cs];
      }
      #pragma unroll
      for (int nt = 0; nt < 2; ++nt) {
        int row = wn * 32 + nt * 16 + (l & 15);
        bh[nt] = *(const half8*)&Bhi[row][cs];
        bl[nt] = *(const half8*)&Blo[row][cs];
      }
      #pragma unroll
      for (int mt = 0; mt < 4; ++mt)
        #pragma unroll
        for (int nt = 0; nt < 2; ++nt) {
          accA[mt][nt] = MFMA16(ah[mt], bh[nt], accA[mt][nt]);
          accB[mt][nt] = MFMA16(ah[mt], bl[nt], accB[mt][nt]);
          accB[mt][nt] = MFMA16(al[mt], bh[nt], accB[mt][nt]);
        }
    }
  }

  npA[t] = nrmA; npB[t] = nrmB;
  __syncthreads();
  if (t < 128) a2s[t] = npA[2*t] + npA[2*t + 1];
  if (t < 64)  q2s[t] = npB[4*t] + npB[4*t + 1] + npB[4*t + 2] + npB[4*t + 3];
  __syncthreads();

  #pragma unroll
  for (int nt = 0; nt < 2; ++nt) {
    float q2 = q2s[wn * 32 + nt * 16 + (l & 15)];
    float bv = 3.0e38f; int bi = 0;
    #pragma unroll
    for (int mt = 0; mt < 4; ++mt)
      #pragma unroll
      for (int r = 0; r < 4; ++r) {
        float dot = accA[mt][nt][r] + accB[mt][nt][r] * INV2K;
        int ml = wm * 64 + mt * 16 + (l >> 4) * 4 + r;
        float d = (q2 + a2s[ml]) - 2.0f * dot;
        if (d < bv) { bv = d; bi = m0 + ml; }
      }
    #pragma unroll
    for (int mm = 16; mm < 64; mm <<= 1) {
      float ov = __shfl_xor(bv, mm, 64);
      int oi = __shfl_xor(bi, mm, 64);
      if (ov < bv || (ov == bv && oi < bi)) { bv = ov; bi = oi; }
    }
    if ((l >> 4) == 0) { redv[wm][wn*32 + nt*16 + l] = bv; redi[wm][wn*32 + nt*16 + l] = bi; }
  }
  __syncthreads();
  if (t < 64) {
    float v0 = redv[0][t]; int i0 = redi[0][t];
    float v1 = redv[1][t]; int i1 = redi[1][t];
    if (v1 < v0) { v0 = v1; i0 = i1; }
    pval[((size_t)b * NCC + n0 + t) * NCHUNK + chunk] = v0;
    pidx[((size_t)b * NCC + n0 + t) * NCHUNK + chunk] = i0;
  }
}

__global__ __launch_bounds__(192) void fine_kernel(
    const float* __restrict__ f1, const float* __restrict__ fkf,
    const int* __restrict__ coarse, int* __restrict__ outf) {
  __shared__ _Float16 Qhi[16][256], Qlo[16][256];
  __shared__ float qn[16], cn[144];
  __shared__ int cROW[144];
  __shared__ int cbr[9], cbc[9];
  __shared__ float redv[3][16];
  __shared__ int   redi[3][16];

  const int t = threadIdx.x;
  const int j = blockIdx.x, i = blockIdx.y, b = blockIdx.z;
  const int l = t & 63, wv = t >> 6;

  if (t < 9) {
    int di = t / 3 - 1, dj = t % 3 - 1;
    int y = min(max(i + di, 0), HCC - 1);
    int x = min(max(j + dj, 0), WCC - 1);
    int base = ((b*HCC + y)*WCC + x) * 2;
    cbr[t] = coarse[base];
    cbc[t] = coarse[base + 1];
  }
  __syncthreads();
  if (t < 144) {
    int n9 = t >> 4, s = t & 15;
    int row = cbr[n9]*DCC + (s >> 2), col = cbc[n9]*DCC + (s & 3);
    cROW[t] = (b*HFF + row)*WFF + col;
  }
  if (t < 64) {
    int qr = l & 15, qq = l >> 4;
    int fr = i*DCC + (qr >> 2), fc = j*DCC + (qr & 3);
    const float* src = fkf + ((size_t)(b*HFF + fr)*WFF + fc) * KFF + qq * 64;
    float s2 = 0.f;
    #pragma unroll
    for (int c2 = 0; c2 < 8; ++c2) {
      float4 u0 = *(const float4*)(src + c2*8);
      float4 u1 = *(const float4*)(src + c2*8 + 4);
      s2 += u0.x*u0.x + u0.y*u0.y + u0.z*u0.z + u0.w*u0.w
          + u1.x*u1.x + u1.y*u1.y + u1.z*u1.z + u1.w*u1.w;
      half8 hh, hl;
      cvt8(u0, u1, hh, hl);
      int cs = (qq * 8 + c2) ^ (qr & 7);
      *(half8*)&Qhi[qr][cs * 8] = hh;
      *(half8*)&Qlo[qr][cs * 8] = hl;
    }
    s2 += __shfl_xor(s2, 16, 64);
    s2 += __shfl_xor(s2, 32, 64);
    if (qq == 0) qn[qr] = s2;
  }
  __syncthreads();

  const float* ap[3];
  #pragma unroll
  for (int T = 0; T < 3; ++T)
    ap[T] = f1 + (size_t)cROW[(wv*3 + T)*16 + (l & 15)] * KFF;

  f32x4 accA[3], accB[3];
  float nrmp[3];
  #pragma unroll
  for (int T = 0; T < 3; ++T) { accA[T] = (f32x4)0.f; accB[T] = (f32x4)0.f; nrmp[T] = 0.f; }

  #pragma unroll 2
  for (int s = 0; s < 8; ++s) {
    const int cs = ((s * 4 + (l >> 4)) ^ (l & 7)) * 8;
    half8 bh = *(const half8*)&Qhi[l & 15][cs];
    half8 bl = *(const half8*)&Qlo[l & 15][cs];
    #pragma unroll
    for (int T = 0; T < 3; ++T) {
      const float* p = ap[T] + s*32 + (l >> 4)*8;
      float4 u0 = *(const float4*)p;
      float4 u1 = *(const float4*)(p + 4);
      nrmp[T] += u0.x*u0.x + u0.y*u0.y + u0.z*u0.z + u0.w*u0.w
               + u1.x*u1.x + u1.y*u1.y + u1.z*u1.z + u1.w*u1.w;
      half8 ahv, alv;
      cvt8(u0, u1, ahv, alv);
      accA[T] = MFMA16(ahv, bh, accA[T]);
      accB[T] = MFMA16(ahv, bl, accB[T]);
      accB[T] = MFMA16(alv, bh, accB[T]);
    }
  }

  #pragma unroll
  for (int T = 0; T < 3; ++T) {
    float np = nrmp[T];
    np += __shfl_xor(np, 16, 64);
    np += __shfl_xor(np, 32, 64);
    if ((l >> 4) == 0) cn[(wv*3 + T)*16 + l] = np;
  }
  __syncthreads();

  {
    float q2 = qn[l & 15];
    float bv = 3.0e38f; int bi = 0;
    #pragma unroll
    for (int T = 0; T < 3; ++T)
      #pragma unroll
      for (int r = 0; r < 4; ++r) {
        float dot = accA[T][r] + accB[T][r] * INV2K;
        int m = (wv*3 + T)*16 + (l >> 4)*4 + r;
        float d = (q2 + cn[m]) - 2.0f * dot;
        if (d < bv) { bv = d; bi = m; }
      }
    #pragma unroll
    for (int mm = 16; mm < 64; mm <<= 1) {
      float ov = __shfl_xor(bv, mm, 64);
      int oi = __shfl_xor(bi, mm, 64);
      if (ov < bv || (ov == bv && oi < bi)) { bv = ov; bi = oi; }
    }
    if ((l >> 4) == 0 && l < 16) { redv[wv][l] = bv; redi[wv][l] = bi; }
  }
  __syncthreads();

  if (t < 16) {
    float v = redv[0][t]; int ix = redi[0][t];
    #pragma unroll
    for (int w = 1; w < 3; ++w) {
      float ov = redv[w][t];
      if (ov < v) { v = ov; ix = redi[w][t]; }
    }
    int n9 = ix >> 4, s3 = ix & 15;
    int br = cbr[n9]*DCC + (s3 >> 2);
    int bc = cbc[n9]*DCC + (s3 & 3);
    int fr = i*DCC + (t >> 2), fc = j*DCC + (t & 3);
    size_t ob = ((size_t)(b*HFF + fr)*WFF + fc) * 2;
    outf[ob]     = br;
    outf[ob + 1] = bc;
  }
}

extern "C" void kernel_launch(void* const* d_in, const int* in_sizes, int n_in,
                              void* d_out, int out_size, void* d_ws, size_t ws_size,
                              hipStream_t stream) {
  (void)in_sizes; (void)n_in; (void)out_size;
  const float* f1c = (const float*)d_in[0];
  const float* fkc = (const float*)d_in[1];
  const float* f1f = (const float*)d_in[2];
  const float* fkf = (const float*)d_in[3];
  int* out = (int*)d_out;

  const size_t NEED = 101220352;  // planes + norms + partials
  if (ws_size >= NEED) {
    char* w = (char*)d_ws;
    _Float16* cAhi = (_Float16*)(w);
    _Float16* cAlo = (_Float16*)(w + 8388608);
    _Float16* cBhi = (_Float16*)(w + 16777216);
    _Float16* cBlo = (_Float16*)(w + 25165824);
    _Float16* fHL  = (_Float16*)(w + 33554432);   // interleaved hi/lo, 67108864 B
    float* na_c = (float*)(w + 100663296);
    float* nq_c = (float*)(w + 100679680);
    float* na_f = (float*)(w + 100696064);
    float* pval = (float*)(w + 100958208);
    int*   pidx = (int*)  (w + 101089280);

    preconv_kernel<KCC><<<dim3(BB*NCC/4, 2), 256, 0, stream>>>(
        f1c, fkc, cAhi, cAlo, cBhi, cBlo, na_c, nq_c, BB*NCC);
    preconv_fine_kernel<<<dim3(BB*HFF*WFF/4), 256, 0, stream>>>(
        f1f, fHL, na_f, BB*HFF*WFF);
    coarse_kernel2<<<dim3(NCHUNK, NCC/64, BB), 256, 0, stream>>>(
        cAhi, cAlo, cBhi, cBlo, na_c, nq_c, pval, pidx);
    coarse_reduce_kernel<<<dim3((BB*NCC + 255)/256), 256, 0, stream>>>(pval, pidx, out);
    fine_kernel3<<<dim3(WCC, HCC, BB), 576, 0, stream>>>(
        fHL, fkf, na_f, out, out + BB*NCC*2);
  } else {
    float* pval = (float*)d_ws;
    int*   pidx = (int*)((float*)d_ws + BB*NCC*NCHUNK);
    coarse_kernel<<<dim3(NCHUNK, NCC/64, BB), 256, 0, stream>>>(f1c, fkc, pval, pidx);
    coarse_reduce_kernel<<<dim3((BB*NCC + 255)/256), 256, 0, stream>>>(pval, pidx, out);
    fine_kernel<<<dim3(WCC, HCC, BB), 192, 0, stream>>>(f1f, fkf, out, out + BB*NCC*2);
  }
}

// Round 6
// 118.204 us; speedup vs baseline: 1.4513x; 1.4513x over previous
//
#include <hip/hip_runtime.h>
#include <cstdint>
#include <cstddef>

#define BB 4
#define HCC 32
#define WCC 32
#define KCC 1024
#define NCC (HCC*WCC)
#define HFF 128
#define WFF 128
#define KFF 256
#define DCC 4
#define NCHUNK 8

typedef _Float16 half8 __attribute__((ext_vector_type(8)));
typedef _Float16 half4_t __attribute__((ext_vector_type(4)));
typedef float f32x4 __attribute__((ext_vector_type(4)));
#define MFMA16(a,b,c) __builtin_amdgcn_mfma_f32_16x16x32_f16((a),(b),(c),0,0,0)
#define INV2K 0.00048828125f

// split fp32 -> (hi fp16, lo' = fp16(2048*(x-hi))).  dot = S1 + S2/2048.
__device__ inline void cvt8(const float4 u0, const float4 u1, half8& h, half8& l2) {
  float uu[8];
  *(float4*)uu = u0; *(float4*)(uu + 4) = u1;
  #pragma unroll
  for (int e = 0; e < 8; ++e) {
    _Float16 hh = (_Float16)uu[e];
    float r = (uu[e] - (float)hh) * 2048.0f;
    h[e] = hh; l2[e] = (_Float16)r;
  }
}

// ======== pre-convert (coarse): fp32 rows -> separate hi/lo planes + norms ========
template<int K>
__global__ __launch_bounds__(256) void preconv_kernel(
    const float* __restrict__ src0, const float* __restrict__ src1,
    _Float16* __restrict__ hi0, _Float16* __restrict__ lo0,
    _Float16* __restrict__ hi1, _Float16* __restrict__ lo1,
    float* __restrict__ nr0, float* __restrict__ nr1, int rows) {
  const float* __restrict__ src = blockIdx.y ? src1 : src0;
  _Float16* __restrict__ hi = blockIdx.y ? hi1 : hi0;
  _Float16* __restrict__ lo = blockIdx.y ? lo1 : lo0;
  float* __restrict__ nrm = blockIdx.y ? nr1 : nr0;
  const int wave = threadIdx.x >> 6, lane = threadIdx.x & 63;
  const int row = blockIdx.x * 4 + wave;
  if (row >= rows) return;
  const float* p = src + (size_t)row * K;
  const size_t ob = (size_t)row * K + lane * 4;
  float s = 0.f;
  #pragma unroll
  for (int c = 0; c < K / 256; ++c) {
    float4 v = *(const float4*)(p + c * 256 + lane * 4);
    s += v.x*v.x + v.y*v.y + v.z*v.z + v.w*v.w;
    float vv[4] = {v.x, v.y, v.z, v.w};
    half4_t h, l2;
    #pragma unroll
    for (int e = 0; e < 4; ++e) {
      _Float16 hh = (_Float16)vv[e];
      l2[e] = (_Float16)((vv[e] - (float)hh) * 2048.0f);
      h[e] = hh;
    }
    *(half4_t*)(hi + ob + c * 256) = h;
    *(half4_t*)(lo + ob + c * 256) = l2;
  }
  #pragma unroll
  for (int m = 1; m <= 32; m <<= 1) s += __shfl_xor(s, m, 64);
  if (lane == 0) nrm[row] = s;
}

// ======== pre-convert (fine): fp32 rows (K=256) -> interleaved [hi8|lo8] + norms ====
// layout per row: 512 halfs, chunk S (0..7, k-step of 32): [S*64 .. S*64+63] = q=0..3 x {hi8, lo8}
__global__ __launch_bounds__(256) void preconv_fine_kernel(
    const float* __restrict__ src, _Float16* __restrict__ hl,
    float* __restrict__ nrm, int rows) {
  const int wave = threadIdx.x >> 6, lane = threadIdx.x & 63;
  const int row = blockIdx.x * 4 + wave;
  if (row >= rows) return;
  float4 v = *(const float4*)(src + (size_t)row * KFF + lane * 4);
  float s = v.x*v.x + v.y*v.y + v.z*v.z + v.w*v.w;
  float vv[4] = {v.x, v.y, v.z, v.w};
  half4_t h, l2;
  #pragma unroll
  for (int e = 0; e < 4; ++e) {
    _Float16 hh = (_Float16)vv[e];
    l2[e] = (_Float16)((vv[e] - (float)hh) * 2048.0f);
    h[e] = hh;
  }
  const size_t dst = (size_t)row * 512 + (lane >> 3) * 64 + ((lane >> 1) & 3) * 16 + (lane & 1) * 4;
  *(half4_t*)(hl + dst)     = h;
  *(half4_t*)(hl + dst + 8) = l2;
  #pragma unroll
  for (int m = 1; m <= 32; m <<= 1) s += __shfl_xor(s, m, 64);
  if (lane == 0) nrm[row] = s;
}

// ======== coarse v2: plane inputs, 128 cands x 64 queries, fp16x3 MFMA ========
__global__ __launch_bounds__(256, 2) void coarse_kernel2(
    const _Float16* __restrict__ gAhi, const _Float16* __restrict__ gAlo,
    const _Float16* __restrict__ gBhi, const _Float16* __restrict__ gBlo,
    const float* __restrict__ na, const float* __restrict__ nq,
    float* __restrict__ pval, int* __restrict__ pidx) {
  __shared__ _Float16 Ahi[128][64], Alo[128][64];
  __shared__ _Float16 Bhi[64][64],  Blo[64][64];
  __shared__ float a2s[128], q2s[64];
  __shared__ float redv[2][64];
  __shared__ int   redi[2][64];

  const int t = threadIdx.x;
  const int chunk = blockIdx.x;
  const int n0 = blockIdx.y * 64;
  const int b  = blockIdx.z;
  const int m0 = chunk * 128;

  const int ar = t >> 1, ahf = t & 1;
  const int brw = t >> 2, bq = t & 3;
  const int l  = t & 63;
  const int wv = t >> 6;
  const int wm = wv >> 1, wn = wv & 1;

  if (t < 128) a2s[t] = na[b*NCC + m0 + t];
  else if (t < 192) q2s[t - 128] = nq[b*NCC + n0 + (t - 128)];

  const _Float16* __restrict__ gah = gAhi + (size_t)(b*NCC + m0 + ar) * KCC + ahf * 32;
  const _Float16* __restrict__ gal = gAlo + (size_t)(b*NCC + m0 + ar) * KCC + ahf * 32;
  const _Float16* __restrict__ gbh = gBhi + (size_t)(b*NCC + n0 + brw) * KCC + bq * 16;
  const _Float16* __restrict__ gbl = gBlo + (size_t)(b*NCC + n0 + brw) * KCC + bq * 16;

  f32x4 accA[4][2], accB[4][2];
  #pragma unroll
  for (int mt = 0; mt < 4; ++mt)
    #pragma unroll
    for (int nt = 0; nt < 2; ++nt) { accA[mt][nt] = (f32x4)0.f; accB[mt][nt] = (f32x4)0.f; }

  for (int k0 = 0; k0 < KCC; k0 += 64) {
    __syncthreads();
    #pragma unroll
    for (int c2 = 0; c2 < 4; ++c2) {
      half8 h  = *(const half8*)(gah + k0 + c2 * 8);
      half8 l8 = *(const half8*)(gal + k0 + c2 * 8);
      int cs = (ahf * 4 + c2) ^ (ar & 7);
      *(half8*)&Ahi[ar][cs * 8] = h;
      *(half8*)&Alo[ar][cs * 8] = l8;
    }
    #pragma unroll
    for (int c2 = 0; c2 < 2; ++c2) {
      half8 h  = *(const half8*)(gbh + k0 + c2 * 8);
      half8 l8 = *(const half8*)(gbl + k0 + c2 * 8);
      int cs = (bq * 2 + c2) ^ (brw & 7);
      *(half8*)&Bhi[brw][cs * 8] = h;
      *(half8*)&Blo[brw][cs * 8] = l8;
    }
    __syncthreads();

    #pragma unroll
    for (int kk = 0; kk < 2; ++kk) {
      const int cs = ((kk * 4 + (l >> 4)) ^ (l & 7)) * 8;
      half8 ah[4], al[4], bh[2], bl[2];
      #pragma unroll
      for (int mt = 0; mt < 4; ++mt) {
        int row = wm * 64 + mt * 16 + (l & 15);
        ah[mt] = *(const half8*)&Ahi[row][cs];
        al[mt] = *(const half8*)&Alo[row][cs];
      }
      #pragma unroll
      for (int nt = 0; nt < 2; ++nt) {
        int row = wn * 32 + nt * 16 + (l & 15);
        bh[nt] = *(const half8*)&Bhi[row][cs];
        bl[nt] = *(const half8*)&Blo[row][cs];
      }
      #pragma unroll
      for (int mt = 0; mt < 4; ++mt)
        #pragma unroll
        for (int nt = 0; nt < 2; ++nt) {
          accA[mt][nt] = MFMA16(ah[mt], bh[nt], accA[mt][nt]);
          accB[mt][nt] = MFMA16(ah[mt], bl[nt], accB[mt][nt]);
          accB[mt][nt] = MFMA16(al[mt], bh[nt], accB[mt][nt]);
        }
    }
  }

  #pragma unroll
  for (int nt = 0; nt < 2; ++nt) {
    float q2 = q2s[wn * 32 + nt * 16 + (l & 15)];
    float bv = 3.0e38f; int bi = 0;
    #pragma unroll
    for (int mt = 0; mt < 4; ++mt)
      #pragma unroll
      for (int r = 0; r < 4; ++r) {
        float dot = accA[mt][nt][r] + accB[mt][nt][r] * INV2K;
        int ml = wm * 64 + mt * 16 + (l >> 4) * 4 + r;
        float d = (q2 + a2s[ml]) - 2.0f * dot;
        if (d < bv) { bv = d; bi = m0 + ml; }
      }
    #pragma unroll
    for (int mm = 16; mm < 64; mm <<= 1) {
      float ov = __shfl_xor(bv, mm, 64);
      int oi = __shfl_xor(bi, mm, 64);
      if (ov < bv || (ov == bv && oi < bi)) { bv = ov; bi = oi; }
    }
    if ((l >> 4) == 0) { redv[wm][wn*32 + nt*16 + l] = bv; redi[wm][wn*32 + nt*16 + l] = bi; }
  }
  __syncthreads();
  if (t < 64) {
    float v0 = redv[0][t]; int i0 = redi[0][t];
    float v1 = redv[1][t]; int i1 = redi[1][t];
    if (v1 < v0) { v0 = v1; i0 = i1; }
    pval[((size_t)b * NCC + n0 + t) * NCHUNK + chunk] = v0;
    pidx[((size_t)b * NCC + n0 + t) * NCHUNK + chunk] = i0;
  }
}

// ======== coarse: combine chunk partials ========
__global__ __launch_bounds__(256) void coarse_reduce_kernel(
    const float* __restrict__ pval, const int* __restrict__ pidx,
    int* __restrict__ out) {
  int g = blockIdx.x * 256 + threadIdx.x;
  if (g >= BB * NCC) return;
  float bv = pval[(size_t)g * NCHUNK];
  int bi = pidx[(size_t)g * NCHUNK];
  #pragma unroll
  for (int c = 1; c < NCHUNK; ++c) {
    float v = pval[(size_t)g * NCHUNK + c];
    int ix = pidx[(size_t)g * NCHUNK + c];
    if (v < bv) { bv = v; bi = ix; }
  }
  out[(size_t)g*2]     = bi >> 5;
  out[(size_t)g*2 + 1] = bi & 31;
}

// ======== fine v4: cell-tiled dedup. block = 4x4 cells, 16 waves, 1 wave/cell ====
// 6x6 target window (576 cand rows) staged in LDS per k-slice of 32 dims.
__global__ __launch_bounds__(1024, 4) void fine_kernel4(
    const _Float16* __restrict__ gHL, const float* __restrict__ fkf,
    const float* __restrict__ naf, const int* __restrict__ coarse,
    int* __restrict__ outf) {
  __shared__ _Float16 CS[576 * 64];   // 72KB: cand k-slice, [row][8 chunks of 16B swz]
  __shared__ _Float16 QS[256 * 64];   // 32KB: query k-slice
  __shared__ int   rIdx[576];
  __shared__ float tNORM[576];
  __shared__ float QN4[256][4];
  __shared__ int cbr[36], cbc[36];

  const int t = threadIdx.x;
  const int bx = blockIdx.x, by = blockIdx.y, b = blockIdx.z;
  const int l = t & 63, w = t >> 6;          // wave = cell
  const int cy = w >> 2, cx = w & 3;
  const int ii = by * 4 + cy, jj = bx * 4 + cx;

  if (t < 36) {
    int wy = t / 6, wx = t % 6;
    int y = min(max(by * 4 - 1 + wy, 0), HCC - 1);
    int x = min(max(bx * 4 - 1 + wx, 0), WCC - 1);
    int base = ((b * HCC + y) * WCC + x) * 2;
    cbr[t] = coarse[base]; cbc[t] = coarse[base + 1];
  }
  __syncthreads();
  if (t < 576) {
    int slot = t >> 4, s = t & 15;
    int row = cbr[slot] * DCC + (s >> 2), col = cbc[slot] * DCC + (s & 3);
    int g = (b * HFF + row) * WFF + col;
    rIdx[t] = g; tNORM[t] = naf[g];
  }
  // Q staging assignment: 256 rows x 4 parts (8 floats each)
  const int qrow = t >> 2, qpart = t & 3;
  const int qcell = qrow >> 4, qs = qrow & 15;
  const int qfr = (by * 4 + (qcell >> 2)) * DCC + (qs >> 2);
  const int qfc = (bx * 4 + (qcell & 3)) * DCC + (qs & 3);
  const float* qsrc = fkf + ((size_t)(b * HFF + qfr) * WFF + qfc) * KFF + qpart * 8;
  const int qswz = qrow & 7;
  float qnp = 0.f;
  __syncthreads();

  f32x4 accA[9], accB[9];
  #pragma unroll
  for (int T = 0; T < 9; ++T) { accA[T] = (f32x4)0.f; accB[T] = (f32x4)0.f; }

  const int q = l >> 4, r = l & 15;
  const int rsw = r & 7;
  const int woff[9] = {0, 1, 2, 6, 7, 8, 12, 13, 14};
  const int wbase = cy * 6 + cx;

  for (int ke = 0; ke < 8; ++ke) {
    // ---- stage CS: 4608 16B chunks, coalesced 128B runs from gHL ----
    #pragma unroll
    for (int it = 0; it < 5; ++it) {
      int g2 = it * 1024 + t;
      if (g2 < 4608) {
        int rowG = g2 >> 3, lc = g2 & 7;
        const _Float16* src = gHL + (size_t)rIdx[rowG] * 512 + ke * 64
                              + (lc >> 1) * 16 + (lc & 1) * 8;
        half8 v = *(const half8*)src;
        *(half8*)&CS[rowG * 64 + (lc ^ (rowG & 7)) * 8] = v;
      }
    }
    // ---- stage QS (fp32 -> hi/lo) + norm partial accumulate ----
    {
      float4 u0 = *(const float4*)(qsrc + ke * 32);
      float4 u1 = *(const float4*)(qsrc + ke * 32 + 4);
      qnp += u0.x*u0.x + u0.y*u0.y + u0.z*u0.z + u0.w*u0.w
           + u1.x*u1.x + u1.y*u1.y + u1.z*u1.z + u1.w*u1.w;
      half8 hh, hl;
      cvt8(u0, u1, hh, hl);
      *(half8*)&QS[qrow * 64 + ((qpart * 2)     ^ qswz) * 8] = hh;
      *(half8*)&QS[qrow * 64 + ((qpart * 2 + 1) ^ qswz) * 8] = hl;
      if (ke == 7) { QN4[qrow][qpart] = qnp; }
    }
    __syncthreads();
    // ---- compute: 9 targets x (2 LDS reads + 3 MFMA) ----
    half8 bh = *(const half8*)&QS[(w * 16 + r) * 64 + ((q * 2)     ^ rsw) * 8];
    half8 bl = *(const half8*)&QS[(w * 16 + r) * 64 + ((q * 2 + 1) ^ rsw) * 8];
    #pragma unroll
    for (int T = 0; T < 9; ++T) {
      int rowG = (wbase + woff[T]) * 16 + r;
      half8 ah = *(const half8*)&CS[rowG * 64 + ((q * 2)     ^ rsw) * 8];
      half8 al = *(const half8*)&CS[rowG * 64 + ((q * 2 + 1) ^ rsw) * 8];
      accA[T] = MFMA16(ah, bh, accA[T]);
      accB[T] = MFMA16(ah, bl, accB[T]);
      accB[T] = MFMA16(al, bh, accB[T]);
    }
    __syncthreads();
  }

  // ---- epilogue: dist + wave-local argmin (first-index ties) ----
  {
    float q2v = QN4[w * 16 + r][0] + QN4[w * 16 + r][1]
              + QN4[w * 16 + r][2] + QN4[w * 16 + r][3];
    float bv = 3.0e38f; int bi = 0;
    #pragma unroll
    for (int T = 0; T < 9; ++T) {
      int slot = wbase + woff[T];
      #pragma unroll
      for (int r2 = 0; r2 < 4; ++r2) {
        int s4 = q * 4 + r2;
        float cn = tNORM[slot * 16 + s4];
        float dot = accA[T][r2] + accB[T][r2] * INV2K;
        float d = (q2v + cn) - 2.0f * dot;
        int m = T * 16 + s4;
        if (d < bv) { bv = d; bi = m; }
      }
    }
    #pragma unroll
    for (int mm = 16; mm < 64; mm <<= 1) {
      float ov = __shfl_xor(bv, mm, 64);
      int oi = __shfl_xor(bi, mm, 64);
      if (ov < bv || (ov == bv && oi < bi)) { bv = ov; bi = oi; }
    }
    if (l < 16) {
      int T = bi >> 4, s3 = bi & 15, slot = wbase + woff[T];
      int br = cbr[slot] * DCC + (s3 >> 2);
      int bc = cbc[slot] * DCC + (s3 & 3);
      int fr = ii * DCC + (l >> 2), fc = jj * DCC + (l & 3);
      size_t ob = ((size_t)(b * HFF + fr) * WFF + fc) * 2;
      outf[ob]     = br;
      outf[ob + 1] = bc;
    }
  }
}

// ================== R3 fallback path (used if ws too small) ==================
__global__ __launch_bounds__(256, 2) void coarse_kernel(
    const float* __restrict__ f1, const float* __restrict__ fk,
    float* __restrict__ pval, int* __restrict__ pidx) {
  __shared__ _Float16 Ahi[128][64], Alo[128][64];
  __shared__ _Float16 Bhi[64][64],  Blo[64][64];
  __shared__ float npA[256], npB[256];
  __shared__ float a2s[128], q2s[64];
  __shared__ float redv[2][64];
  __shared__ int   redi[2][64];

  const int t = threadIdx.x;
  const int chunk = blockIdx.x;
  const int n0 = blockIdx.y * 64;
  const int b  = blockIdx.z;
  const int m0 = chunk * 128;

  const float* __restrict__ Abase = f1 + ((size_t)b * NCC + m0) * KCC;
  const float* __restrict__ Bbase = fk + ((size_t)b * NCC + n0) * KCC;

  const int ar = t >> 1, ahf = t & 1;
  const int brw = t >> 2, bq = t & 3;
  const int l  = t & 63;
  const int wv = t >> 6;
  const int wm = wv >> 1, wn = wv & 1;

  float nrmA = 0.f, nrmB = 0.f;
  f32x4 accA[4][2], accB[4][2];
  #pragma unroll
  for (int mt = 0; mt < 4; ++mt)
    #pragma unroll
    for (int nt = 0; nt < 2; ++nt) { accA[mt][nt] = (f32x4)0.f; accB[mt][nt] = (f32x4)0.f; }

  for (int k0 = 0; k0 < KCC; k0 += 64) {
    __syncthreads();
    {
      const float4* src = (const float4*)(Abase + (size_t)ar * KCC + k0 + ahf * 32);
      float4 va[8];
      #pragma unroll
      for (int i2 = 0; i2 < 8; ++i2) va[i2] = src[i2];
      #pragma unroll
      for (int i2 = 0; i2 < 8; ++i2)
        nrmA += va[i2].x*va[i2].x + va[i2].y*va[i2].y + va[i2].z*va[i2].z + va[i2].w*va[i2].w;
      #pragma unroll
      for (int c2 = 0; c2 < 4; ++c2) {
        half8 hh, hl;
        cvt8(va[c2*2], va[c2*2+1], hh, hl);
        int cs = (ahf * 4 + c2) ^ (ar & 7);
        *(half8*)&Ahi[ar][cs * 8] = hh;
        *(half8*)&Alo[ar][cs * 8] = hl;
      }
    }
    {
      const float4* src = (const float4*)(Bbase + (size_t)brw * KCC + k0 + bq * 16);
      float4 vb[4];
      #pragma unroll
      for (int i2 = 0; i2 < 4; ++i2) vb[i2] = src[i2];
      #pragma unroll
      for (int i2 = 0; i2 < 4; ++i2)
        nrmB += vb[i2].x*vb[i2].x + vb[i2].y*vb[i2].y + vb[i2].z*vb[i2].z + vb[i2].w*vb[i2].w;
      #pragma unroll
      for (int c2 = 0; c2 < 2; ++c2) {
        half8 hh, hl;
        cvt8(vb[c2*2], vb[c2*2+1], hh, hl);
        int cs = (bq * 2 + c2) ^ (brw & 7);
        *(half8*)&Bhi[brw][cs * 8] = hh;
        *(half8*)&Blo[brw][cs * 8] = hl;
      }
    }
    __syncthreads();

    #pragma unroll
    for (int kk = 0; kk < 2; ++kk) {
      const int cs = ((kk * 4 + (l >> 4)) ^ (l & 7)) * 8;
      half8 ah[4], al[4], bh[2], bl[2];
      #pragma unroll
      for (int mt = 0; mt < 4; ++mt) {
        int row = wm * 64 + mt * 16 + (l & 15);
        ah[mt] = *(const half8*)&Ahi[row][cs];
        al[mt] = *(const half8*)&Alo[row][cs];
      }
      #pragma unroll
      for (int nt = 0; nt < 2; ++nt) {
        int row = wn * 32 + nt * 16 + (l & 15);
        bh[nt] = *(const half8*)&Bhi[row][cs];
        bl[nt] = *(const half8*)&Blo[row][cs];
      }
      #pragma unroll
      for (int mt = 0; mt < 4; ++mt)
        #pragma unroll
        for (int nt = 0; nt < 2; ++nt) {
          accA[mt][nt] = MFMA16(ah[mt], bh[nt], accA[mt][nt]);
          accB[mt][nt] = MFMA16(ah[mt], bl[nt], accB[mt][nt]);
          accB[mt][nt] = MFMA16(al[mt], bh[nt], accB[mt][nt]);
        }
    }
  }

  npA[t] = nrmA; npB[t] = nrmB;
  __syncthreads();
  if (t < 128) a2s[t] = npA[2*t] + npA[2*t + 1];
  if (t < 64)  q2s[t] = npB[4*t] + npB[4*t + 1] + npB[4*t + 2] + npB[4*t + 3];
  __syncthreads();

  #pragma unroll
  for (int nt = 0; nt < 2; ++nt) {
    float q2 = q2s[wn * 32 + nt * 16 + (l & 15)];
    float bv = 3.0e38f; int bi = 0;
    #pragma unroll
    for (int mt = 0; mt < 4; ++mt)
      #pragma unroll
      for (int r = 0; r < 4; ++r) {
        float dot = accA[mt][nt][r] + accB[mt][nt][r] * INV2K;
        int ml = wm * 64 + mt * 16 + (l >> 4) * 4 + r;
        float d = (q2 + a2s[ml]) - 2.0f * dot;
        if (d < bv) { bv = d; bi = m0 + ml; }
      }
    #pragma unroll
    for (int mm = 16; mm < 64; mm <<= 1) {
      float ov = __shfl_xor(bv, mm, 64);
      int oi = __shfl_xor(bi, mm, 64);
      if (ov < bv || (ov == bv && oi < bi)) { bv = ov; bi = oi; }
    }
    if ((l >> 4) == 0) { redv[wm][wn*32 + nt*16 + l] = bv; redi[wm][wn*32 + nt*16 + l] = bi; }
  }
  __syncthreads();
  if (t < 64) {
    float v0 = redv[0][t]; int i0 = redi[0][t];
    float v1 = redv[1][t]; int i1 = redi[1][t];
    if (v1 < v0) { v0 = v1; i0 = i1; }
    pval[((size_t)b * NCC + n0 + t) * NCHUNK + chunk] = v0;
    pidx[((size_t)b * NCC + n0 + t) * NCHUNK + chunk] = i0;
  }
}

__global__ __launch_bounds__(192) void fine_kernel(
    const float* __restrict__ f1, const float* __restrict__ fkf,
    const int* __restrict__ coarse, int* __restrict__ outf) {
  __shared__ _Float16 Qhi[16][256], Qlo[16][256];
  __shared__ float qn[16], cn[144];
  __shared__ int cROW[144];
  __shared__ int cbr[9], cbc[9];
  __shared__ float redv[3][16];
  __shared__ int   redi[3][16];

  const int t = threadIdx.x;
  const int j = blockIdx.x, i = blockIdx.y, b = blockIdx.z;
  const int l = t & 63, wv = t >> 6;

  if (t < 9) {
    int di = t / 3 - 1, dj = t % 3 - 1;
    int y = min(max(i + di, 0), HCC - 1);
    int x = min(max(j + dj, 0), WCC - 1);
    int base = ((b*HCC + y)*WCC + x) * 2;
    cbr[t] = coarse[base];
    cbc[t] = coarse[base + 1];
  }
  __syncthreads();
  if (t < 144) {
    int n9 = t >> 4, s = t & 15;
    int row = cbr[n9]*DCC + (s >> 2), col = cbc[n9]*DCC + (s & 3);
    cROW[t] = (b*HFF + row)*WFF + col;
  }
  if (t < 64) {
    int qr = l & 15, qq = l >> 4;
    int fr = i*DCC + (qr >> 2), fc = j*DCC + (qr & 3);
    const float* src = fkf + ((size_t)(b*HFF + fr)*WFF + fc) * KFF + qq * 64;
    float s2 = 0.f;
    #pragma unroll
    for (int c2 = 0; c2 < 8; ++c2) {
      float4 u0 = *(const float4*)(src + c2*8);
      float4 u1 = *(const float4*)(src + c2*8 + 4);
      s2 += u0.x*u0.x + u0.y*u0.y + u0.z*u0.z + u0.w*u0.w
          + u1.x*u1.x + u1.y*u1.y + u1.z*u1.z + u1.w*u1.w;
      half8 hh, hl;
      cvt8(u0, u1, hh, hl);
      int cs = (qq * 8 + c2) ^ (qr & 7);
      *(half8*)&Qhi[qr][cs * 8] = hh;
      *(half8*)&Qlo[qr][cs * 8] = hl;
    }
    s2 += __shfl_xor(s2, 16, 64);
    s2 += __shfl_xor(s2, 32, 64);
    if (qq == 0) qn[qr] = s2;
  }
  __syncthreads();

  const float* ap[3];
  #pragma unroll
  for (int T = 0; T < 3; ++T)
    ap[T] = f1 + (size_t)cROW[(wv*3 + T)*16 + (l & 15)] * KFF;

  f32x4 accA[3], accB[3];
  float nrmp[3];
  #pragma unroll
  for (int T = 0; T < 3; ++T) { accA[T] = (f32x4)0.f; accB[T] = (f32x4)0.f; nrmp[T] = 0.f; }

  #pragma unroll 2
  for (int s = 0; s < 8; ++s) {
    const int cs = ((s * 4 + (l >> 4)) ^ (l & 7)) * 8;
    half8 bh = *(const half8*)&Qhi[l & 15][cs];
    half8 bl = *(const half8*)&Qlo[l & 15][cs];
    #pragma unroll
    for (int T = 0; T < 3; ++T) {
      const float* p = ap[T] + s*32 + (l >> 4)*8;
      float4 u0 = *(const float4*)p;
      float4 u1 = *(const float4*)(p + 4);
      nrmp[T] += u0.x*u0.x + u0.y*u0.y + u0.z*u0.z + u0.w*u0.w
               + u1.x*u1.x + u1.y*u1.y + u1.z*u1.z + u1.w*u1.w;
      half8 ahv, alv;
      cvt8(u0, u1, ahv, alv);
      accA[T] = MFMA16(ahv, bh, accA[T]);
      accB[T] = MFMA16(ahv, bl, accB[T]);
      accB[T] = MFMA16(alv, bh, accB[T]);
    }
  }

  #pragma unroll
  for (int T = 0; T < 3; ++T) {
    float np = nrmp[T];
    np += __shfl_xor(np, 16, 64);
    np += __shfl_xor(np, 32, 64);
    if ((l >> 4) == 0) cn[(wv*3 + T)*16 + l] = np;
  }
  __syncthreads();

  {
    float q2 = qn[l & 15];
    float bv = 3.0e38f; int bi = 0;
    #pragma unroll
    for (int T = 0; T < 3; ++T)
      #pragma unroll
      for (int r = 0; r < 4; ++r) {
        float dot = accA[T][r] + accB[T][r] * INV2K;
        int m = (wv*3 + T)*16 + (l >> 4)*4 + r;
        float d = (q2 + cn[m]) - 2.0f * dot;
        if (d < bv) { bv = d; bi = m; }
      }
    #pragma unroll
    for (int mm = 16; mm < 64; mm <<= 1) {
      float ov = __shfl_xor(bv, mm, 64);
      int oi = __shfl_xor(bi, mm, 64);
      if (ov < bv || (ov == bv && oi < bi)) { bv = ov; bi = oi; }
    }
    if ((l >> 4) == 0 && l < 16) { redv[wv][l] = bv; redi[wv][l] = bi; }
  }
  __syncthreads();

  if (t < 16) {
    float v = redv[0][t]; int ix = redi[0][t];
    #pragma unroll
    for (int w = 1; w < 3; ++w) {
      float ov = redv[w][t];
      if (ov < v) { v = ov; ix = redi[w][t]; }
    }
    int n9 = ix >> 4, s3 = ix & 15;
    int br = cbr[n9]*DCC + (s3 >> 2);
    int bc = cbc[n9]*DCC + (s3 & 3);
    int fr = i*DCC + (t >> 2), fc = j*DCC + (t & 3);
    size_t ob = ((size_t)(b*HFF + fr)*WFF + fc) * 2;
    outf[ob]     = br;
    outf[ob + 1] = bc;
  }
}

extern "C" void kernel_launch(void* const* d_in, const int* in_sizes, int n_in,
                              void* d_out, int out_size, void* d_ws, size_t ws_size,
                              hipStream_t stream) {
  (void)in_sizes; (void)n_in; (void)out_size;
  const float* f1c = (const float*)d_in[0];
  const float* fkc = (const float*)d_in[1];
  const float* f1f = (const float*)d_in[2];
  const float* fkf = (const float*)d_in[3];
  int* out = (int*)d_out;

  const size_t NEED = 101220352;  // planes + norms + partials
  if (ws_size >= NEED) {
    char* w = (char*)d_ws;
    _Float16* cAhi = (_Float16*)(w);
    _Float16* cAlo = (_Float16*)(w + 8388608);
    _Float16* cBhi = (_Float16*)(w + 16777216);
    _Float16* cBlo = (_Float16*)(w + 25165824);
    _Float16* fHL  = (_Float16*)(w + 33554432);   // interleaved hi/lo, 67108864 B
    float* na_c = (float*)(w + 100663296);
    float* nq_c = (float*)(w + 100679680);
    float* na_f = (float*)(w + 100696064);
    float* pval = (float*)(w + 100958208);
    int*   pidx = (int*)  (w + 101089280);

    preconv_kernel<KCC><<<dim3(BB*NCC/4, 2), 256, 0, stream>>>(
        f1c, fkc, cAhi, cAlo, cBhi, cBlo, na_c, nq_c, BB*NCC);
    preconv_fine_kernel<<<dim3(BB*HFF*WFF/4), 256, 0, stream>>>(
        f1f, fHL, na_f, BB*HFF*WFF);
    coarse_kernel2<<<dim3(NCHUNK, NCC/64, BB), 256, 0, stream>>>(
        cAhi, cAlo, cBhi, cBlo, na_c, nq_c, pval, pidx);
    coarse_reduce_kernel<<<dim3((BB*NCC + 255)/256), 256, 0, stream>>>(pval, pidx, out);
    fine_kernel4<<<dim3(WCC/4, HCC/4, BB), 1024, 0, stream>>>(
        fHL, fkf, na_f, out, out + BB*NCC*2);
  } else {
    float* pval = (float*)d_ws;
    int*   pidx = (int*)((float*)d_ws + BB*NCC*NCHUNK);
    coarse_kernel<<<dim3(NCHUNK, NCC/64, BB), 256, 0, stream>>>(f1c, fkc, pval, pidx);
    coarse_reduce_kernel<<<dim3((BB*NCC + 255)/256), 256, 0, stream>>>(pval, pidx, out);
    fine_kernel<<<dim3(WCC, HCC, BB), 192, 0, stream>>>(f1f, fkf, out, out + BB*NCC*2);
  }
}

// Round 7
// 112.388 us; speedup vs baseline: 1.5264x; 1.0518x over previous
//
#include <hip/hip_runtime.h>
#include <cstdint>
#include <cstddef>

#define BB 4
#define HCC 32
#define WCC 32
#define KCC 1024
#define NCC (HCC*WCC)
#define HFF 128
#define WFF 128
#define KFF 256
#define DCC 4
#define NCHUNK 8

typedef _Float16 half8 __attribute__((ext_vector_type(8)));
typedef _Float16 half4_t __attribute__((ext_vector_type(4)));
typedef float f32x4 __attribute__((ext_vector_type(4)));
#define MFMA16(a,b,c) __builtin_amdgcn_mfma_f32_16x16x32_f16((a),(b),(c),0,0,0)
#define INV2K 0.00048828125f

// split fp32 -> (hi fp16, lo' = fp16(2048*(x-hi))).  dot = S1 + S2/2048.
__device__ inline void cvt8(const float4 u0, const float4 u1, half8& h, half8& l2) {
  float uu[8];
  *(float4*)uu = u0; *(float4*)(uu + 4) = u1;
  #pragma unroll
  for (int e = 0; e < 8; ++e) {
    _Float16 hh = (_Float16)uu[e];
    float r = (uu[e] - (float)hh) * 2048.0f;
    h[e] = hh; l2[e] = (_Float16)r;
  }
}

// ======== pre-convert (coarse): fp32 rows -> separate hi/lo planes + norms ========
template<int K>
__global__ __launch_bounds__(256) void preconv_kernel(
    const float* __restrict__ src0, const float* __restrict__ src1,
    _Float16* __restrict__ hi0, _Float16* __restrict__ lo0,
    _Float16* __restrict__ hi1, _Float16* __restrict__ lo1,
    float* __restrict__ nr0, float* __restrict__ nr1, int rows) {
  const float* __restrict__ src = blockIdx.y ? src1 : src0;
  _Float16* __restrict__ hi = blockIdx.y ? hi1 : hi0;
  _Float16* __restrict__ lo = blockIdx.y ? lo1 : lo0;
  float* __restrict__ nrm = blockIdx.y ? nr1 : nr0;
  const int wave = threadIdx.x >> 6, lane = threadIdx.x & 63;
  const int row = blockIdx.x * 4 + wave;
  if (row >= rows) return;
  const float* p = src + (size_t)row * K;
  const size_t ob = (size_t)row * K + lane * 4;
  float s = 0.f;
  #pragma unroll
  for (int c = 0; c < K / 256; ++c) {
    float4 v = *(const float4*)(p + c * 256 + lane * 4);
    s += v.x*v.x + v.y*v.y + v.z*v.z + v.w*v.w;
    float vv[4] = {v.x, v.y, v.z, v.w};
    half4_t h, l2;
    #pragma unroll
    for (int e = 0; e < 4; ++e) {
      _Float16 hh = (_Float16)vv[e];
      l2[e] = (_Float16)((vv[e] - (float)hh) * 2048.0f);
      h[e] = hh;
    }
    *(half4_t*)(hi + ob + c * 256) = h;
    *(half4_t*)(lo + ob + c * 256) = l2;
  }
  #pragma unroll
  for (int m = 1; m <= 32; m <<= 1) s += __shfl_xor(s, m, 64);
  if (lane == 0) nrm[row] = s;
}

// ======== pre-convert (fine): fp32 rows (K=256) -> interleaved [hi8|lo8] + norms ====
__global__ __launch_bounds__(256) void preconv_fine_kernel(
    const float* __restrict__ src, _Float16* __restrict__ hl,
    float* __restrict__ nrm, int rows) {
  const int wave = threadIdx.x >> 6, lane = threadIdx.x & 63;
  const int row = blockIdx.x * 4 + wave;
  if (row >= rows) return;
  float4 v = *(const float4*)(src + (size_t)row * KFF + lane * 4);
  float s = v.x*v.x + v.y*v.y + v.z*v.z + v.w*v.w;
  float vv[4] = {v.x, v.y, v.z, v.w};
  half4_t h, l2;
  #pragma unroll
  for (int e = 0; e < 4; ++e) {
    _Float16 hh = (_Float16)vv[e];
    l2[e] = (_Float16)((vv[e] - (float)hh) * 2048.0f);
    h[e] = hh;
  }
  const size_t dst = (size_t)row * 512 + (lane >> 3) * 64 + ((lane >> 1) & 3) * 16 + (lane & 1) * 4;
  *(half4_t*)(hl + dst)     = h;
  *(half4_t*)(hl + dst + 8) = l2;
  #pragma unroll
  for (int m = 1; m <= 32; m <<= 1) s += __shfl_xor(s, m, 64);
  if (lane == 0) nrm[row] = s;
}

// ======== coarse v3: register-prefetch pipelined, 128 cands x 64 queries ========
__global__ __launch_bounds__(256) void coarse_kernel3(
    const _Float16* __restrict__ gAhi, const _Float16* __restrict__ gAlo,
    const _Float16* __restrict__ gBhi, const _Float16* __restrict__ gBlo,
    const float* __restrict__ na, const float* __restrict__ nq,
    float* __restrict__ pval, int* __restrict__ pidx) {
  __shared__ _Float16 Ahi[128][64], Alo[128][64];
  __shared__ _Float16 Bhi[64][64],  Blo[64][64];
  __shared__ float a2s[128], q2s[64];
  __shared__ float redv[2][64];
  __shared__ int   redi[2][64];

  const int t = threadIdx.x;
  const int chunk = blockIdx.x;
  const int n0 = blockIdx.y * 64;
  const int b  = blockIdx.z;
  const int m0 = chunk * 128;

  const int ar = t >> 1, ahf = t & 1;
  const int brw = t >> 2, bq = t & 3;
  const int l  = t & 63;
  const int wv = t >> 6;
  const int wm = wv >> 1, wn = wv & 1;

  if (t < 128) a2s[t] = na[b*NCC + m0 + t];
  else if (t < 192) q2s[t - 128] = nq[b*NCC + n0 + (t - 128)];

  const _Float16* __restrict__ gah = gAhi + (size_t)(b*NCC + m0 + ar) * KCC + ahf * 32;
  const _Float16* __restrict__ gal = gAlo + (size_t)(b*NCC + m0 + ar) * KCC + ahf * 32;
  const _Float16* __restrict__ gbh = gBhi + (size_t)(b*NCC + n0 + brw) * KCC + bq * 16;
  const _Float16* __restrict__ gbl = gBlo + (size_t)(b*NCC + n0 + brw) * KCC + bq * 16;

  f32x4 accA[4][2], accB[4][2];
  #pragma unroll
  for (int mt = 0; mt < 4; ++mt)
    #pragma unroll
    for (int nt = 0; nt < 2; ++nt) { accA[mt][nt] = (f32x4)0.f; accB[mt][nt] = (f32x4)0.f; }

  // prefetch k0 = 0
  half8 pah[4], pal[4], pbh[2], pbl[2];
  #pragma unroll
  for (int c2 = 0; c2 < 4; ++c2) { pah[c2] = *(const half8*)(gah + c2*8); pal[c2] = *(const half8*)(gal + c2*8); }
  #pragma unroll
  for (int c2 = 0; c2 < 2; ++c2) { pbh[c2] = *(const half8*)(gbh + c2*8); pbl[c2] = *(const half8*)(gbl + c2*8); }

  for (int k0 = 0; k0 < KCC; k0 += 64) {
    __syncthreads();      // previous compute done reading LDS
    #pragma unroll
    for (int c2 = 0; c2 < 4; ++c2) {
      int cs = (ahf * 4 + c2) ^ (ar & 7);
      *(half8*)&Ahi[ar][cs * 8] = pah[c2];
      *(half8*)&Alo[ar][cs * 8] = pal[c2];
    }
    #pragma unroll
    for (int c2 = 0; c2 < 2; ++c2) {
      int cs = (bq * 2 + c2) ^ (brw & 7);
      *(half8*)&Bhi[brw][cs * 8] = pbh[c2];
      *(half8*)&Blo[brw][cs * 8] = pbl[c2];
    }
    __syncthreads();      // LDS ready

    if (k0 + 64 < KCC) {  // prefetch next k-step; latency hides under MFMA phase
      #pragma unroll
      for (int c2 = 0; c2 < 4; ++c2) {
        pah[c2] = *(const half8*)(gah + k0 + 64 + c2*8);
        pal[c2] = *(const half8*)(gal + k0 + 64 + c2*8);
      }
      #pragma unroll
      for (int c2 = 0; c2 < 2; ++c2) {
        pbh[c2] = *(const half8*)(gbh + k0 + 64 + c2*8);
        pbl[c2] = *(const half8*)(gbl + k0 + 64 + c2*8);
      }
    }

    #pragma unroll
    for (int kk = 0; kk < 2; ++kk) {
      const int cs = ((kk * 4 + (l >> 4)) ^ (l & 7)) * 8;
      half8 ah[4], al[4], bh[2], bl[2];
      #pragma unroll
      for (int mt = 0; mt < 4; ++mt) {
        int row = wm * 64 + mt * 16 + (l & 15);
        ah[mt] = *(const half8*)&Ahi[row][cs];
        al[mt] = *(const half8*)&Alo[row][cs];
      }
      #pragma unroll
      for (int nt = 0; nt < 2; ++nt) {
        int row = wn * 32 + nt * 16 + (l & 15);
        bh[nt] = *(const half8*)&Bhi[row][cs];
        bl[nt] = *(const half8*)&Blo[row][cs];
      }
      #pragma unroll
      for (int mt = 0; mt < 4; ++mt)
        #pragma unroll
        for (int nt = 0; nt < 2; ++nt) {
          accA[mt][nt] = MFMA16(ah[mt], bh[nt], accA[mt][nt]);
          accB[mt][nt] = MFMA16(ah[mt], bl[nt], accB[mt][nt]);
          accB[mt][nt] = MFMA16(al[mt], bh[nt], accB[mt][nt]);
        }
    }
  }

  #pragma unroll
  for (int nt = 0; nt < 2; ++nt) {
    float q2 = q2s[wn * 32 + nt * 16 + (l & 15)];
    float bv = 3.0e38f; int bi = 0;
    #pragma unroll
    for (int mt = 0; mt < 4; ++mt)
      #pragma unroll
      for (int r = 0; r < 4; ++r) {
        float dot = accA[mt][nt][r] + accB[mt][nt][r] * INV2K;
        int ml = wm * 64 + mt * 16 + (l >> 4) * 4 + r;
        float d = (q2 + a2s[ml]) - 2.0f * dot;
        if (d < bv) { bv = d; bi = m0 + ml; }
      }
    #pragma unroll
    for (int mm = 16; mm < 64; mm <<= 1) {
      float ov = __shfl_xor(bv, mm, 64);
      int oi = __shfl_xor(bi, mm, 64);
      if (ov < bv || (ov == bv && oi < bi)) { bv = ov; bi = oi; }
    }
    if ((l >> 4) == 0) { redv[wm][wn*32 + nt*16 + l] = bv; redi[wm][wn*32 + nt*16 + l] = bi; }
  }
  __syncthreads();
  if (t < 64) {
    float v0 = redv[0][t]; int i0 = redi[0][t];
    float v1 = redv[1][t]; int i1 = redi[1][t];
    if (v1 < v0) { v0 = v1; i0 = i1; }
    pval[((size_t)b * NCC + n0 + t) * NCHUNK + chunk] = v0;
    pidx[((size_t)b * NCC + n0 + t) * NCHUNK + chunk] = i0;
  }
}

// ======== coarse: combine chunk partials ========
__global__ __launch_bounds__(256) void coarse_reduce_kernel(
    const float* __restrict__ pval, const int* __restrict__ pidx,
    int* __restrict__ out) {
  int g = blockIdx.x * 256 + threadIdx.x;
  if (g >= BB * NCC) return;
  float bv = pval[(size_t)g * NCHUNK];
  int bi = pidx[(size_t)g * NCHUNK];
  #pragma unroll
  for (int c = 1; c < NCHUNK; ++c) {
    float v = pval[(size_t)g * NCHUNK + c];
    int ix = pidx[(size_t)g * NCHUNK + c];
    if (v < bv) { bv = v; bi = ix; }
  }
  out[(size_t)g*2]     = bi >> 5;
  out[(size_t)g*2 + 1] = bi & 31;
}

// ======== fine v5: 2x4 cells/block, 8 waves, 2 blocks/CU, reg-prefetch pipeline ====
__global__ __launch_bounds__(512) void fine_kernel5(
    const _Float16* __restrict__ gHL, const float* __restrict__ fkf,
    const float* __restrict__ naf, const int* __restrict__ coarse,
    int* __restrict__ outf) {
  __shared__ _Float16 CS[384 * 64];   // 48KB: cand k-slice (4x6 slot window)
  __shared__ _Float16 QS[128 * 64];   // 16KB: query k-slice
  __shared__ int   rIdx[384];
  __shared__ float tNORM[384];
  __shared__ float QN4[128][4];
  __shared__ int cbr[24], cbc[24];

  const int t = threadIdx.x;
  const int bx = blockIdx.x, by = blockIdx.y, b = blockIdx.z;
  const int l = t & 63, w = t >> 6;          // wave = cell, 2x4
  const int cy = w >> 2, cx = w & 3;
  const int ii = by * 2 + cy, jj = bx * 4 + cx;

  if (t < 24) {
    int wy = t / 6, wx = t % 6;
    int y = min(max(by * 2 - 1 + wy, 0), HCC - 1);
    int x = min(max(bx * 4 - 1 + wx, 0), WCC - 1);
    int base = ((b * HCC + y) * WCC + x) * 2;
    cbr[t] = coarse[base]; cbc[t] = coarse[base + 1];
  }
  __syncthreads();
  if (t < 384) {
    int slot = t >> 4, s = t & 15;
    int row = cbr[slot] * DCC + (s >> 2), col = cbc[slot] * DCC + (s & 3);
    int g = (b * HFF + row) * WFF + col;
    rIdx[t] = g; tNORM[t] = naf[g];
  }
  __syncthreads();

  // CS staging geometry: 384 rows x 8 chunks = 3072 = 6 per thread
  unsigned srcOff[6], dstOff[6];
  #pragma unroll
  for (int it = 0; it < 6; ++it) {
    int g2 = it * 512 + t;
    int rowG = g2 >> 3, lc = g2 & 7;
    srcOff[it] = (unsigned)rIdx[rowG] * 512u + (unsigned)((lc >> 1) * 16 + (lc & 1) * 8);
    dstOff[it] = (unsigned)(rowG * 64 + (lc ^ (rowG & 7)) * 8);
  }
  // Q staging: 128 rows x 4 parts = 512, 1 per thread
  const int qrow = t >> 2, qpart = t & 3;
  const int qcell = qrow >> 4, qs = qrow & 15;
  const int qfr = (by * 2 + (qcell >> 2)) * DCC + (qs >> 2);
  const int qfc = (bx * 4 + (qcell & 3)) * DCC + (qs & 3);
  const float* qsrc = fkf + ((size_t)(b * HFF + qfr) * WFF + qfc) * KFF + qpart * 8;
  const int qswz = qrow & 7;
  float qnp = 0.f;

  // prefetch slice 0
  half8 pf[6];
  #pragma unroll
  for (int it = 0; it < 6; ++it) pf[it] = *(const half8*)(gHL + srcOff[it]);
  float4 qu0 = *(const float4*)(qsrc);
  float4 qu1 = *(const float4*)(qsrc + 4);

  f32x4 accA[9], accB[9];
  #pragma unroll
  for (int T = 0; T < 9; ++T) { accA[T] = (f32x4)0.f; accB[T] = (f32x4)0.f; }

  const int q = l >> 4, r = l & 15;
  const int rsw = r & 7;
  const int woff[9] = {0, 1, 2, 6, 7, 8, 12, 13, 14};
  const int wbase = cy * 6 + cx;

  for (int ke = 0; ke < 8; ++ke) {
    __syncthreads();                      // prev compute done reading LDS
    #pragma unroll
    for (int it = 0; it < 6; ++it) *(half8*)&CS[dstOff[it]] = pf[it];
    {
      qnp += qu0.x*qu0.x + qu0.y*qu0.y + qu0.z*qu0.z + qu0.w*qu0.w
           + qu1.x*qu1.x + qu1.y*qu1.y + qu1.z*qu1.z + qu1.w*qu1.w;
      half8 hh, hl;
      cvt8(qu0, qu1, hh, hl);
      *(half8*)&QS[qrow * 64 + ((qpart * 2)     ^ qswz) * 8] = hh;
      *(half8*)&QS[qrow * 64 + ((qpart * 2 + 1) ^ qswz) * 8] = hl;
      if (ke == 7) QN4[qrow][qpart] = qnp;
    }
    __syncthreads();                      // LDS ready

    if (ke < 7) {                         // prefetch next slice under compute
      #pragma unroll
      for (int it = 0; it < 6; ++it)
        pf[it] = *(const half8*)(gHL + srcOff[it] + (unsigned)(ke + 1) * 64u);
      qu0 = *(const float4*)(qsrc + (ke + 1) * 32);
      qu1 = *(const float4*)(qsrc + (ke + 1) * 32 + 4);
    }

    half8 bh = *(const half8*)&QS[(w * 16 + r) * 64 + ((q * 2)     ^ rsw) * 8];
    half8 bl = *(const half8*)&QS[(w * 16 + r) * 64 + ((q * 2 + 1) ^ rsw) * 8];
    #pragma unroll
    for (int T = 0; T < 9; ++T) {
      int rowG = (wbase + woff[T]) * 16 + r;
      half8 ah = *(const half8*)&CS[rowG * 64 + ((q * 2)     ^ rsw) * 8];
      half8 al = *(const half8*)&CS[rowG * 64 + ((q * 2 + 1) ^ rsw) * 8];
      accA[T] = MFMA16(ah, bh, accA[T]);
      accB[T] = MFMA16(ah, bl, accB[T]);
      accB[T] = MFMA16(al, bh, accB[T]);
    }
  }

  // ---- epilogue: dist + wave-local argmin (first-index ties) ----
  {
    float q2v = QN4[w * 16 + r][0] + QN4[w * 16 + r][1]
              + QN4[w * 16 + r][2] + QN4[w * 16 + r][3];
    float bv = 3.0e38f; int bi = 0;
    #pragma unroll
    for (int T = 0; T < 9; ++T) {
      int slot = wbase + woff[T];
      #pragma unroll
      for (int r2 = 0; r2 < 4; ++r2) {
        int s4 = q * 4 + r2;
        float cn = tNORM[slot * 16 + s4];
        float dot = accA[T][r2] + accB[T][r2] * INV2K;
        float d = (q2v + cn) - 2.0f * dot;
        int m = T * 16 + s4;
        if (d < bv) { bv = d; bi = m; }
      }
    }
    #pragma unroll
    for (int mm = 16; mm < 64; mm <<= 1) {
      float ov = __shfl_xor(bv, mm, 64);
      int oi = __shfl_xor(bi, mm, 64);
      if (ov < bv || (ov == bv && oi < bi)) { bv = ov; bi = oi; }
    }
    if (l < 16) {
      int T = bi >> 4, s3 = bi & 15, slot = wbase + woff[T];
      int br = cbr[slot] * DCC + (s3 >> 2);
      int bc = cbc[slot] * DCC + (s3 & 3);
      int fr = ii * DCC + (l >> 2), fc = jj * DCC + (l & 3);
      size_t ob = ((size_t)(b * HFF + fr) * WFF + fc) * 2;
      outf[ob]     = br;
      outf[ob + 1] = bc;
    }
  }
}

// ================== R3 fallback path (used if ws too small) ==================
__global__ __launch_bounds__(256, 2) void coarse_kernel(
    const float* __restrict__ f1, const float* __restrict__ fk,
    float* __restrict__ pval, int* __restrict__ pidx) {
  __shared__ _Float16 Ahi[128][64], Alo[128][64];
  __shared__ _Float16 Bhi[64][64],  Blo[64][64];
  __shared__ float npA[256], npB[256];
  __shared__ float a2s[128], q2s[64];
  __shared__ float redv[2][64];
  __shared__ int   redi[2][64];

  const int t = threadIdx.x;
  const int chunk = blockIdx.x;
  const int n0 = blockIdx.y * 64;
  const int b  = blockIdx.z;
  const int m0 = chunk * 128;

  const float* __restrict__ Abase = f1 + ((size_t)b * NCC + m0) * KCC;
  const float* __restrict__ Bbase = fk + ((size_t)b * NCC + n0) * KCC;

  const int ar = t >> 1, ahf = t & 1;
  const int brw = t >> 2, bq = t & 3;
  const int l  = t & 63;
  const int wv = t >> 6;
  const int wm = wv >> 1, wn = wv & 1;

  float nrmA = 0.f, nrmB = 0.f;
  f32x4 accA[4][2], accB[4][2];
  #pragma unroll
  for (int mt = 0; mt < 4; ++mt)
    #pragma unroll
    for (int nt = 0; nt < 2; ++nt) { accA[mt][nt] = (f32x4)0.f; accB[mt][nt] = (f32x4)0.f; }

  for (int k0 = 0; k0 < KCC; k0 += 64) {
    __syncthreads();
    {
      const float4* src = (const float4*)(Abase + (size_t)ar * KCC + k0 + ahf * 32);
      float4 va[8];
      #pragma unroll
      for (int i2 = 0; i2 < 8; ++i2) va[i2] = src[i2];
      #pragma unroll
      for (int i2 = 0; i2 < 8; ++i2)
        nrmA += va[i2].x*va[i2].x + va[i2].y*va[i2].y + va[i2].z*va[i2].z + va[i2].w*va[i2].w;
      #pragma unroll
      for (int c2 = 0; c2 < 4; ++c2) {
        half8 hh, hl;
        cvt8(va[c2*2], va[c2*2+1], hh, hl);
        int cs = (ahf * 4 + c2) ^ (ar & 7);
        *(half8*)&Ahi[ar][cs * 8] = hh;
        *(half8*)&Alo[ar][cs * 8] = hl;
      }
    }
    {
      const float4* src = (const float4*)(Bbase + (size_t)brw * KCC + k0 + bq * 16);
      float4 vb[4];
      #pragma unroll
      for (int i2 = 0; i2 < 4; ++i2) vb[i2] = src[i2];
      #pragma unroll
      for (int i2 = 0; i2 < 4; ++i2)
        nrmB += vb[i2].x*vb[i2].x + vb[i2].y*vb[i2].y + vb[i2].z*vb[i2].z + vb[i2].w*vb[i2].w;
      #pragma unroll
      for (int c2 = 0; c2 < 2; ++c2) {
        half8 hh, hl;
        cvt8(vb[c2*2], vb[c2*2+1], hh, hl);
        int cs = (bq * 2 + c2) ^ (brw & 7);
        *(half8*)&Bhi[brw][cs * 8] = hh;
        *(half8*)&Blo[brw][cs * 8] = hl;
      }
    }
    __syncthreads();

    #pragma unroll
    for (int kk = 0; kk < 2; ++kk) {
      const int cs = ((kk * 4 + (l >> 4)) ^ (l & 7)) * 8;
      half8 ah[4], al[4], bh[2], bl[2];
      #pragma unroll
      for (int mt = 0; mt < 4; ++mt) {
        int row = wm * 64 + mt * 16 + (l & 15);
        ah[mt] = *(const half8*)&Ahi[row][cs];
        al[mt] = *(const half8*)&Alo[row][cs];
      }
      #pragma unroll
      for (int nt = 0; nt < 2; ++nt) {
        int row = wn * 32 + nt * 16 + (l & 15);
        bh[nt] = *(const half8*)&Bhi[row][cs];
        bl[nt] = *(const half8*)&Blo[row][cs];
      }
      #pragma unroll
      for (int mt = 0; mt < 4; ++mt)
        #pragma unroll
        for (int nt = 0; nt < 2; ++nt) {
          accA[mt][nt] = MFMA16(ah[mt], bh[nt], accA[mt][nt]);
          accB[mt][nt] = MFMA16(ah[mt], bl[nt], accB[mt][nt]);
          accB[mt][nt] = MFMA16(al[mt], bh[nt], accB[mt][nt]);
        }
    }
  }

  npA[t] = nrmA; npB[t] = nrmB;
  __syncthreads();
  if (t < 128) a2s[t] = npA[2*t] + npA[2*t + 1];
  if (t < 64)  q2s[t] = npB[4*t] + npB[4*t + 1] + npB[4*t + 2] + npB[4*t + 3];
  __syncthreads();

  #pragma unroll
  for (int nt = 0; nt < 2; ++nt) {
    float q2 = q2s[wn * 32 + nt * 16 + (l & 15)];
    float bv = 3.0e38f; int bi = 0;
    #pragma unroll
    for (int mt = 0; mt < 4; ++mt)
      #pragma unroll
      for (int r = 0; r < 4; ++r) {
        float dot = accA[mt][nt][r] + accB[mt][nt][r] * INV2K;
        int ml = wm * 64 + mt * 16 + (l >> 4) * 4 + r;
        float d = (q2 + a2s[ml]) - 2.0f * dot;
        if (d < bv) { bv = d; bi = m0 + ml; }
      }
    #pragma unroll
    for (int mm = 16; mm < 64; mm <<= 1) {
      float ov = __shfl_xor(bv, mm, 64);
      int oi = __shfl_xor(bi, mm, 64);
      if (ov < bv || (ov == bv && oi < bi)) { bv = ov; bi = oi; }
    }
    if ((l >> 4) == 0) { redv[wm][wn*32 + nt*16 + l] = bv; redi[wm][wn*32 + nt*16 + l] = bi; }
  }
  __syncthreads();
  if (t < 64) {
    float v0 = redv[0][t]; int i0 = redi[0][t];
    float v1 = redv[1][t]; int i1 = redi[1][t];
    if (v1 < v0) { v0 = v1; i0 = i1; }
    pval[((size_t)b * NCC + n0 + t) * NCHUNK + chunk] = v0;
    pidx[((size_t)b * NCC + n0 + t) * NCHUNK + chunk] = i0;
  }
}

__global__ __launch_bounds__(192) void fine_kernel(
    const float* __restrict__ f1, const float* __restrict__ fkf,
    const int* __restrict__ coarse, int* __restrict__ outf) {
  __shared__ _Float16 Qhi[16][256], Qlo[16][256];
  __shared__ float qn[16], cn[144];
  __shared__ int cROW[144];
  __shared__ int cbr[9], cbc[9];
  __shared__ float redv[3][16];
  __shared__ int   redi[3][16];

  const int t = threadIdx.x;
  const int j = blockIdx.x, i = blockIdx.y, b = blockIdx.z;
  const int l = t & 63, wv = t >> 6;

  if (t < 9) {
    int di = t / 3 - 1, dj = t % 3 - 1;
    int y = min(max(i + di, 0), HCC - 1);
    int x = min(max(j + dj, 0), WCC - 1);
    int base = ((b*HCC + y)*WCC + x) * 2;
    cbr[t] = coarse[base];
    cbc[t] = coarse[base + 1];
  }
  __syncthreads();
  if (t < 144) {
    int n9 = t >> 4, s = t & 15;
    int row = cbr[n9]*DCC + (s >> 2), col = cbc[n9]*DCC + (s & 3);
    cROW[t] = (b*HFF + row)*WFF + col;
  }
  if (t < 64) {
    int qr = l & 15, qq = l >> 4;
    int fr = i*DCC + (qr >> 2), fc = j*DCC + (qr & 3);
    const float* src = fkf + ((size_t)(b*HFF + fr)*WFF + fc) * KFF + qq * 64;
    float s2 = 0.f;
    #pragma unroll
    for (int c2 = 0; c2 < 8; ++c2) {
      float4 u0 = *(const float4*)(src + c2*8);
      float4 u1 = *(const float4*)(src + c2*8 + 4);
      s2 += u0.x*u0.x + u0.y*u0.y + u0.z*u0.z + u0.w*u0.w
          + u1.x*u1.x + u1.y*u1.y + u1.z*u1.z + u1.w*u1.w;
      half8 hh, hl;
      cvt8(u0, u1, hh, hl);
      int cs = (qq * 8 + c2) ^ (qr & 7);
      *(half8*)&Qhi[qr][cs * 8] = hh;
      *(half8*)&Qlo[qr][cs * 8] = hl;
    }
    s2 += __shfl_xor(s2, 16, 64);
    s2 += __shfl_xor(s2, 32, 64);
    if (qq == 0) qn[qr] = s2;
  }
  __syncthreads();

  const float* ap[3];
  #pragma unroll
  for (int T = 0; T < 3; ++T)
    ap[T] = f1 + (size_t)cROW[(wv*3 + T)*16 + (l & 15)] * KFF;

  f32x4 accA[3], accB[3];
  float nrmp[3];
  #pragma unroll
  for (int T = 0; T < 3; ++T) { accA[T] = (f32x4)0.f; accB[T] = (f32x4)0.f; nrmp[T] = 0.f; }

  #pragma unroll 2
  for (int s = 0; s < 8; ++s) {
    const int cs = ((s * 4 + (l >> 4)) ^ (l & 7)) * 8;
    half8 bh = *(const half8*)&Qhi[l & 15][cs];
    half8 bl = *(const half8*)&Qlo[l & 15][cs];
    #pragma unroll
    for (int T = 0; T < 3; ++T) {
      const float* p = ap[T] + s*32 + (l >> 4)*8;
      float4 u0 = *(const float4*)p;
      float4 u1 = *(const float4*)(p + 4);
      nrmp[T] += u0.x*u0.x + u0.y*u0.y + u0.z*u0.z + u0.w*u0.w
               + u1.x*u1.x + u1.y*u1.y + u1.z*u1.z + u1.w*u1.w;
      half8 ahv, alv;
      cvt8(u0, u1, ahv, alv);
      accA[T] = MFMA16(ahv, bh, accA[T]);
      accB[T] = MFMA16(ahv, bl, accB[T]);
      accB[T] = MFMA16(alv, bh, accB[T]);
    }
  }

  #pragma unroll
  for (int T = 0; T < 3; ++T) {
    float np = nrmp[T];
    np += __shfl_xor(np, 16, 64);
    np += __shfl_xor(np, 32, 64);
    if ((l >> 4) == 0) cn[(wv*3 + T)*16 + l] = np;
  }
  __syncthreads();

  {
    float q2 = qn[l & 15];
    float bv = 3.0e38f; int bi = 0;
    #pragma unroll
    for (int T = 0; T < 3; ++T)
      #pragma unroll
      for (int r = 0; r < 4; ++r) {
        float dot = accA[T][r] + accB[T][r] * INV2K;
        int m = (wv*3 + T)*16 + (l >> 4)*4 + r;
        float d = (q2 + cn[m]) - 2.0f * dot;
        if (d < bv) { bv = d; bi = m; }
      }
    #pragma unroll
    for (int mm = 16; mm < 64; mm <<= 1) {
      float ov = __shfl_xor(bv, mm, 64);
      int oi = __shfl_xor(bi, mm, 64);
      if (ov < bv || (ov == bv && oi < bi)) { bv = ov; bi = oi; }
    }
    if ((l >> 4) == 0 && l < 16) { redv[wv][l] = bv; redi[wv][l] = bi; }
  }
  __syncthreads();

  if (t < 16) {
    float v = redv[0][t]; int ix = redi[0][t];
    #pragma unroll
    for (int w = 1; w < 3; ++w) {
      float ov = redv[w][t];
      if (ov < v) { v = ov; ix = redi[w][t]; }
    }
    int n9 = ix >> 4, s3 = ix & 15;
    int br = cbr[n9]*DCC + (s3 >> 2);
    int bc = cbc[n9]*DCC + (s3 & 3);
    int fr = i*DCC + (t >> 2), fc = j*DCC + (t & 3);
    size_t ob = ((size_t)(b*HFF + fr)*WFF + fc) * 2;
    outf[ob]     = br;
    outf[ob + 1] = bc;
  }
}

extern "C" void kernel_launch(void* const* d_in, const int* in_sizes, int n_in,
                              void* d_out, int out_size, void* d_ws, size_t ws_size,
                              hipStream_t stream) {
  (void)in_sizes; (void)n_in; (void)out_size;
  const float* f1c = (const float*)d_in[0];
  const float* fkc = (const float*)d_in[1];
  const float* f1f = (const float*)d_in[2];
  const float* fkf = (const float*)d_in[3];
  int* out = (int*)d_out;

  const size_t NEED = 101220352;  // planes + norms + partials
  if (ws_size >= NEED) {
    char* w = (char*)d_ws;
    _Float16* cAhi = (_Float16*)(w);
    _Float16* cAlo = (_Float16*)(w + 8388608);
    _Float16* cBhi = (_Float16*)(w + 16777216);
    _Float16* cBlo = (_Float16*)(w + 25165824);
    _Float16* fHL  = (_Float16*)(w + 33554432);   // interleaved hi/lo, 67108864 B
    float* na_c = (float*)(w + 100663296);
    float* nq_c = (float*)(w + 100679680);
    float* na_f = (float*)(w + 100696064);
    float* pval = (float*)(w + 100958208);
    int*   pidx = (int*)  (w + 101089280);

    preconv_kernel<KCC><<<dim3(BB*NCC/4, 2), 256, 0, stream>>>(
        f1c, fkc, cAhi, cAlo, cBhi, cBlo, na_c, nq_c, BB*NCC);
    preconv_fine_kernel<<<dim3(BB*HFF*WFF/4), 256, 0, stream>>>(
        f1f, fHL, na_f, BB*HFF*WFF);
    coarse_kernel3<<<dim3(NCHUNK, NCC/64, BB), 256, 0, stream>>>(
        cAhi, cAlo, cBhi, cBlo, na_c, nq_c, pval, pidx);
    coarse_reduce_kernel<<<dim3((BB*NCC + 255)/256), 256, 0, stream>>>(pval, pidx, out);
    fine_kernel5<<<dim3(WCC/4, HCC/2, BB), 512, 0, stream>>>(
        fHL, fkf, na_f, out, out + BB*NCC*2);
  } else {
    float* pval = (float*)d_ws;
    int*   pidx = (int*)((float*)d_ws + BB*NCC*NCHUNK);
    coarse_kernel<<<dim3(NCHUNK, NCC/64, BB), 256, 0, stream>>>(f1c, fkc, pval, pidx);
    coarse_reduce_kernel<<<dim3((BB*NCC + 255)/256), 256, 0, stream>>>(pval, pidx, out);
    fine_kernel<<<dim3(WCC, HCC, BB), 192, 0, stream>>>(f1f, fkf, out, out + BB*NCC*2);
  }
}

// Round 8
// 104.872 us; speedup vs baseline: 1.6358x; 1.0717x over previous
//
#include <hip/hip_runtime.h>
#include <cstdint>
#include <cstddef>

#define BB 4
#define HCC 32
#define WCC 32
#define KCC 1024
#define NCC (HCC*WCC)
#define HFF 128
#define WFF 128
#define KFF 256
#define DCC 4
#define NCHUNK 8

typedef _Float16 half8 __attribute__((ext_vector_type(8)));
typedef _Float16 half4_t __attribute__((ext_vector_type(4)));
typedef float f32x4 __attribute__((ext_vector_type(4)));
#define MFMA16(a,b,c) __builtin_amdgcn_mfma_f32_16x16x32_f16((a),(b),(c),0,0,0)
#define INV2K 0.00048828125f

// split fp32 -> (hi fp16, lo' = fp16(2048*(x-hi))).  dot = S1 + S2/2048.
__device__ inline void cvt8(const float4 u0, const float4 u1, half8& h, half8& l2) {
  float uu[8];
  *(float4*)uu = u0; *(float4*)(uu + 4) = u1;
  #pragma unroll
  for (int e = 0; e < 8; ++e) {
    _Float16 hh = (_Float16)uu[e];
    float r = (uu[e] - (float)hh) * 2048.0f;
    h[e] = hh; l2[e] = (_Float16)r;
  }
}

// ======== pre-convert (coarse): fp32 rows -> separate hi/lo planes + norms ========
template<int K>
__global__ __launch_bounds__(256) void preconv_kernel(
    const float* __restrict__ src0, const float* __restrict__ src1,
    _Float16* __restrict__ hi0, _Float16* __restrict__ lo0,
    _Float16* __restrict__ hi1, _Float16* __restrict__ lo1,
    float* __restrict__ nr0, float* __restrict__ nr1, int rows) {
  const float* __restrict__ src = blockIdx.y ? src1 : src0;
  _Float16* __restrict__ hi = blockIdx.y ? hi1 : hi0;
  _Float16* __restrict__ lo = blockIdx.y ? lo1 : lo0;
  float* __restrict__ nrm = blockIdx.y ? nr1 : nr0;
  const int wave = threadIdx.x >> 6, lane = threadIdx.x & 63;
  const int row = blockIdx.x * 4 + wave;
  if (row >= rows) return;
  const float* p = src + (size_t)row * K;
  const size_t ob = (size_t)row * K + lane * 4;
  float s = 0.f;
  #pragma unroll
  for (int c = 0; c < K / 256; ++c) {
    float4 v = *(const float4*)(p + c * 256 + lane * 4);
    s += v.x*v.x + v.y*v.y + v.z*v.z + v.w*v.w;
    float vv[4] = {v.x, v.y, v.z, v.w};
    half4_t h, l2;
    #pragma unroll
    for (int e = 0; e < 4; ++e) {
      _Float16 hh = (_Float16)vv[e];
      l2[e] = (_Float16)((vv[e] - (float)hh) * 2048.0f);
      h[e] = hh;
    }
    *(half4_t*)(hi + ob + c * 256) = h;
    *(half4_t*)(lo + ob + c * 256) = l2;
  }
  #pragma unroll
  for (int m = 1; m <= 32; m <<= 1) s += __shfl_xor(s, m, 64);
  if (lane == 0) nrm[row] = s;
}

// ======== pre-convert (fine): fp32 rows (K=256) -> interleaved [hi8|lo8] + norms ====
__global__ __launch_bounds__(256) void preconv_fine_kernel(
    const float* __restrict__ src, _Float16* __restrict__ hl,
    float* __restrict__ nrm, int rows) {
  const int wave = threadIdx.x >> 6, lane = threadIdx.x & 63;
  const int row = blockIdx.x * 4 + wave;
  if (row >= rows) return;
  float4 v = *(const float4*)(src + (size_t)row * KFF + lane * 4);
  float s = v.x*v.x + v.y*v.y + v.z*v.z + v.w*v.w;
  float vv[4] = {v.x, v.y, v.z, v.w};
  half4_t h, l2;
  #pragma unroll
  for (int e = 0; e < 4; ++e) {
    _Float16 hh = (_Float16)vv[e];
    l2[e] = (_Float16)((vv[e] - (float)hh) * 2048.0f);
    h[e] = hh;
  }
  const size_t dst = (size_t)row * 512 + (lane >> 3) * 64 + ((lane >> 1) & 3) * 16 + (lane & 1) * 4;
  *(half4_t*)(hl + dst)     = h;
  *(half4_t*)(hl + dst + 8) = l2;
  #pragma unroll
  for (int m = 1; m <= 32; m <<= 1) s += __shfl_xor(s, m, 64);
  if (lane == 0) nrm[row] = s;
}

// ======== coarse v3: register-prefetch pipelined, 128 cands x 64 queries ========
__global__ __launch_bounds__(256) void coarse_kernel3(
    const _Float16* __restrict__ gAhi, const _Float16* __restrict__ gAlo,
    const _Float16* __restrict__ gBhi, const _Float16* __restrict__ gBlo,
    const float* __restrict__ na, const float* __restrict__ nq,
    float* __restrict__ pval, int* __restrict__ pidx) {
  __shared__ _Float16 Ahi[128][64], Alo[128][64];
  __shared__ _Float16 Bhi[64][64],  Blo[64][64];
  __shared__ float a2s[128], q2s[64];
  __shared__ float redv[2][64];
  __shared__ int   redi[2][64];

  const int t = threadIdx.x;
  const int chunk = blockIdx.x;
  const int n0 = blockIdx.y * 64;
  const int b  = blockIdx.z;
  const int m0 = chunk * 128;

  const int ar = t >> 1, ahf = t & 1;
  const int brw = t >> 2, bq = t & 3;
  const int l  = t & 63;
  const int wv = t >> 6;
  const int wm = wv >> 1, wn = wv & 1;

  if (t < 128) a2s[t] = na[b*NCC + m0 + t];
  else if (t < 192) q2s[t - 128] = nq[b*NCC + n0 + (t - 128)];

  const _Float16* __restrict__ gah = gAhi + (size_t)(b*NCC + m0 + ar) * KCC + ahf * 32;
  const _Float16* __restrict__ gal = gAlo + (size_t)(b*NCC + m0 + ar) * KCC + ahf * 32;
  const _Float16* __restrict__ gbh = gBhi + (size_t)(b*NCC + n0 + brw) * KCC + bq * 16;
  const _Float16* __restrict__ gbl = gBlo + (size_t)(b*NCC + n0 + brw) * KCC + bq * 16;

  f32x4 accA[4][2], accB[4][2];
  #pragma unroll
  for (int mt = 0; mt < 4; ++mt)
    #pragma unroll
    for (int nt = 0; nt < 2; ++nt) { accA[mt][nt] = (f32x4)0.f; accB[mt][nt] = (f32x4)0.f; }

  half8 pah[4], pal[4], pbh[2], pbl[2];
  #pragma unroll
  for (int c2 = 0; c2 < 4; ++c2) { pah[c2] = *(const half8*)(gah + c2*8); pal[c2] = *(const half8*)(gal + c2*8); }
  #pragma unroll
  for (int c2 = 0; c2 < 2; ++c2) { pbh[c2] = *(const half8*)(gbh + c2*8); pbl[c2] = *(const half8*)(gbl + c2*8); }

  for (int k0 = 0; k0 < KCC; k0 += 64) {
    __syncthreads();
    #pragma unroll
    for (int c2 = 0; c2 < 4; ++c2) {
      int cs = (ahf * 4 + c2) ^ (ar & 7);
      *(half8*)&Ahi[ar][cs * 8] = pah[c2];
      *(half8*)&Alo[ar][cs * 8] = pal[c2];
    }
    #pragma unroll
    for (int c2 = 0; c2 < 2; ++c2) {
      int cs = (bq * 2 + c2) ^ (brw & 7);
      *(half8*)&Bhi[brw][cs * 8] = pbh[c2];
      *(half8*)&Blo[brw][cs * 8] = pbl[c2];
    }
    __syncthreads();

    if (k0 + 64 < KCC) {
      #pragma unroll
      for (int c2 = 0; c2 < 4; ++c2) {
        pah[c2] = *(const half8*)(gah + k0 + 64 + c2*8);
        pal[c2] = *(const half8*)(gal + k0 + 64 + c2*8);
      }
      #pragma unroll
      for (int c2 = 0; c2 < 2; ++c2) {
        pbh[c2] = *(const half8*)(gbh + k0 + 64 + c2*8);
        pbl[c2] = *(const half8*)(gbl + k0 + 64 + c2*8);
      }
    }

    #pragma unroll
    for (int kk = 0; kk < 2; ++kk) {
      const int cs = ((kk * 4 + (l >> 4)) ^ (l & 7)) * 8;
      half8 ah[4], al[4], bh[2], bl[2];
      #pragma unroll
      for (int mt = 0; mt < 4; ++mt) {
        int row = wm * 64 + mt * 16 + (l & 15);
        ah[mt] = *(const half8*)&Ahi[row][cs];
        al[mt] = *(const half8*)&Alo[row][cs];
      }
      #pragma unroll
      for (int nt = 0; nt < 2; ++nt) {
        int row = wn * 32 + nt * 16 + (l & 15);
        bh[nt] = *(const half8*)&Bhi[row][cs];
        bl[nt] = *(const half8*)&Blo[row][cs];
      }
      #pragma unroll
      for (int mt = 0; mt < 4; ++mt)
        #pragma unroll
        for (int nt = 0; nt < 2; ++nt) {
          accA[mt][nt] = MFMA16(ah[mt], bh[nt], accA[mt][nt]);
          accB[mt][nt] = MFMA16(ah[mt], bl[nt], accB[mt][nt]);
          accB[mt][nt] = MFMA16(al[mt], bh[nt], accB[mt][nt]);
        }
    }
  }

  #pragma unroll
  for (int nt = 0; nt < 2; ++nt) {
    float q2 = q2s[wn * 32 + nt * 16 + (l & 15)];
    float bv = 3.0e38f; int bi = 0;
    #pragma unroll
    for (int mt = 0; mt < 4; ++mt)
      #pragma unroll
      for (int r = 0; r < 4; ++r) {
        float dot = accA[mt][nt][r] + accB[mt][nt][r] * INV2K;
        int ml = wm * 64 + mt * 16 + (l >> 4) * 4 + r;
        float d = (q2 + a2s[ml]) - 2.0f * dot;
        if (d < bv) { bv = d; bi = m0 + ml; }
      }
    #pragma unroll
    for (int mm = 16; mm < 64; mm <<= 1) {
      float ov = __shfl_xor(bv, mm, 64);
      int oi = __shfl_xor(bi, mm, 64);
      if (ov < bv || (ov == bv && oi < bi)) { bv = ov; bi = oi; }
    }
    if ((l >> 4) == 0) { redv[wm][wn*32 + nt*16 + l] = bv; redi[wm][wn*32 + nt*16 + l] = bi; }
  }
  __syncthreads();
  if (t < 64) {
    float v0 = redv[0][t]; int i0 = redi[0][t];
    float v1 = redv[1][t]; int i1 = redi[1][t];
    if (v1 < v0) { v0 = v1; i0 = i1; }
    pval[((size_t)b * NCC + n0 + t) * NCHUNK + chunk] = v0;
    pidx[((size_t)b * NCC + n0 + t) * NCHUNK + chunk] = i0;
  }
}

// ======== coarse: combine chunk partials ========
__global__ __launch_bounds__(256) void coarse_reduce_kernel(
    const float* __restrict__ pval, const int* __restrict__ pidx,
    int* __restrict__ out) {
  int g = blockIdx.x * 256 + threadIdx.x;
  if (g >= BB * NCC) return;
  float bv = pval[(size_t)g * NCHUNK];
  int bi = pidx[(size_t)g * NCHUNK];
  #pragma unroll
  for (int c = 1; c < NCHUNK; ++c) {
    float v = pval[(size_t)g * NCHUNK + c];
    int ix = pidx[(size_t)g * NCHUNK + c];
    if (v < bv) { bv = v; bi = ix; }
  }
  out[(size_t)g*2]     = bi >> 5;
  out[(size_t)g*2 + 1] = bi & 31;
}

// ======== fine v6: dbuf CS + single barrier/slice + Q in regs ========
// block = 2x4 cells, 8 waves (512 thr), 4x6 slot window (384 rows), 1 block/CU.
__global__ __launch_bounds__(512, 2) void fine_kernel6(
    const _Float16* __restrict__ gHL, const float* __restrict__ fkf,
    const float* __restrict__ naf, const int* __restrict__ coarse,
    int* __restrict__ outf) {
  __shared__ _Float16 CS[2][384 * 64];   // 96KB double-buffered cand slices
  __shared__ int   rIdx[384];
  __shared__ float tNORM[384];
  __shared__ int cbr[24], cbc[24];
  __shared__ float redv[8][16];
  __shared__ int   redi[8][16];

  const int t = threadIdx.x;
  const int bx = blockIdx.x, by = blockIdx.y, b = blockIdx.z;
  const int l = t & 63, w = t >> 6;          // wave = cell, 2x4
  const int cy = w >> 2, cx = w & 3;
  const int ii = by * 2 + cy, jj = bx * 4 + cx;

  if (t < 24) {
    int wy = t / 6, wx = t % 6;
    int y = min(max(by * 2 - 1 + wy, 0), HCC - 1);
    int x = min(max(bx * 4 - 1 + wx, 0), WCC - 1);
    int base = ((b * HCC + y) * WCC + x) * 2;
    cbr[t] = coarse[base]; cbc[t] = coarse[base + 1];
  }
  __syncthreads();
  if (t < 384) {
    int slot = t >> 4, s = t & 15;
    int row = cbr[slot] * DCC + (s >> 2), col = cbc[slot] * DCC + (s & 3);
    int g = (b * HFF + row) * WFF + col;
    rIdx[t] = g; tNORM[t] = naf[g];
  }
  __syncthreads();

  // CS staging geometry: 384 rows x 8 chunks = 3072 = 6 per thread
  unsigned srcOff[6], dstOff[6];
  #pragma unroll
  for (int it = 0; it < 6; ++it) {
    int g2 = it * 512 + t;
    int rowG = g2 >> 3, lc = g2 & 7;
    srcOff[it] = (unsigned)rIdx[rowG] * 512u + (unsigned)((lc >> 1) * 16 + (lc & 1) * 8);
    dstOff[it] = (unsigned)(rowG * 64 + (lc ^ (rowG & 7)) * 8);
  }

  // Q source: lane l = row (l&15) of cell w, k-part q = l>>4
  const int q = l >> 4, r = l & 15;
  const int qfr = ii * DCC + (r >> 2), qfc = jj * DCC + (r & 3);
  const float* qsrc = fkf + ((size_t)(b * HFF + qfr) * WFF + qfc) * KFF + q * 8;

  // prologue: stage slice 0, prefetch slice 1 + Q slice 0
  half8 pf[6];
  #pragma unroll
  for (int it = 0; it < 6; ++it) pf[it] = *(const half8*)(gHL + srcOff[it]);
  #pragma unroll
  for (int it = 0; it < 6; ++it) *(half8*)&CS[0][dstOff[it]] = pf[it];
  #pragma unroll
  for (int it = 0; it < 6; ++it) pf[it] = *(const half8*)(gHL + srcOff[it] + 64u);
  float4 qu0 = *(const float4*)(qsrc);
  float4 qu1 = *(const float4*)(qsrc + 4);
  __syncthreads();

  f32x4 accA[9], accB[9];
  #pragma unroll
  for (int T = 0; T < 9; ++T) { accA[T] = (f32x4)0.f; accB[T] = (f32x4)0.f; }

  const int woff[9] = {0, 1, 2, 6, 7, 8, 12, 13, 14};
  const int wbase = cy * 6 + cx;
  const int rsw = r & 7;
  const int c0 = ((q * 2) ^ rsw) * 8, c1 = ((q * 2 + 1) ^ rsw) * 8;
  float qnp = 0.f;

  #pragma unroll
  for (int ke = 0; ke < 8; ++ke) {
    const int cur = ke & 1;
    // Q: convert prefetched fp32, accumulate norm, prefetch next
    qnp += qu0.x*qu0.x + qu0.y*qu0.y + qu0.z*qu0.z + qu0.w*qu0.w
         + qu1.x*qu1.x + qu1.y*qu1.y + qu1.z*qu1.z + qu1.w*qu1.w;
    half8 bh, bl;
    cvt8(qu0, qu1, bh, bl);
    if (ke < 7) {
      qu0 = *(const float4*)(qsrc + (ke + 1) * 32);
      qu1 = *(const float4*)(qsrc + (ke + 1) * 32 + 4);
    }
    // compute from CS[cur]
    #pragma unroll
    for (int T = 0; T < 9; ++T) {
      int rowG = (wbase + woff[T]) * 16 + r;
      half8 ah = *(const half8*)&CS[cur][rowG * 64 + c0];
      half8 al = *(const half8*)&CS[cur][rowG * 64 + c1];
      accA[T] = MFMA16(ah, bh, accA[T]);
      accB[T] = MFMA16(ah, bl, accB[T]);
      accB[T] = MFMA16(al, bh, accB[T]);
    }
    // stage slice ke+1 into the other buffer; prefetch slice ke+2
    if (ke < 7) {
      #pragma unroll
      for (int it = 0; it < 6; ++it) *(half8*)&CS[cur ^ 1][dstOff[it]] = pf[it];
      if (ke < 6) {
        #pragma unroll
        for (int it = 0; it < 6; ++it)
          pf[it] = *(const half8*)(gHL + srcOff[it] + (unsigned)(ke + 2) * 64u);
      }
    }
    __syncthreads();
  }

  // query norm: reduce over the 4 k-parts (lanes l, l^16, l^32, l^48)
  qnp += __shfl_xor(qnp, 16, 64);
  qnp += __shfl_xor(qnp, 32, 64);
  const float q2v = qnp;

  // ---- epilogue: dist + wave-local argmin (first-index ties) ----
  {
    float bv = 3.0e38f; int bi = 0;
    #pragma unroll
    for (int T = 0; T < 9; ++T) {
      int slot = wbase + woff[T];
      #pragma unroll
      for (int r2 = 0; r2 < 4; ++r2) {
        int s4 = q * 4 + r2;
        float cn = tNORM[slot * 16 + s4];
        float dot = accA[T][r2] + accB[T][r2] * INV2K;
        float d = (q2v + cn) - 2.0f * dot;
        int m = T * 16 + s4;
        if (d < bv) { bv = d; bi = m; }
      }
    }
    #pragma unroll
    for (int mm = 16; mm < 64; mm <<= 1) {
      float ov = __shfl_xor(bv, mm, 64);
      int oi = __shfl_xor(bi, mm, 64);
      if (ov < bv || (ov == bv && oi < bi)) { bv = ov; bi = oi; }
    }
    if (l < 16) {
      int T = bi >> 4, s3 = bi & 15, slot = wbase + woff[T];
      int br = cbr[slot] * DCC + (s3 >> 2);
      int bc = cbc[slot] * DCC + (s3 & 3);
      int fr = ii * DCC + (l >> 2), fc = jj * DCC + (l & 3);
      size_t ob = ((size_t)(b * HFF + fr) * WFF + fc) * 2;
      outf[ob]     = br;
      outf[ob + 1] = bc;
    }
  }
  (void)redv; (void)redi;
}

// ================== R3 fallback path (used if ws too small) ==================
__global__ __launch_bounds__(256, 2) void coarse_kernel(
    const float* __restrict__ f1, const float* __restrict__ fk,
    float* __restrict__ pval, int* __restrict__ pidx) {
  __shared__ _Float16 Ahi[128][64], Alo[128][64];
  __shared__ _Float16 Bhi[64][64],  Blo[64][64];
  __shared__ float npA[256], npB[256];
  __shared__ float a2s[128], q2s[64];
  __shared__ float redv[2][64];
  __shared__ int   redi[2][64];

  const int t = threadIdx.x;
  const int chunk = blockIdx.x;
  const int n0 = blockIdx.y * 64;
  const int b  = blockIdx.z;
  const int m0 = chunk * 128;

  const float* __restrict__ Abase = f1 + ((size_t)b * NCC + m0) * KCC;
  const float* __restrict__ Bbase = fk + ((size_t)b * NCC + n0) * KCC;

  const int ar = t >> 1, ahf = t & 1;
  const int brw = t >> 2, bq = t & 3;
  const int l  = t & 63;
  const int wv = t >> 6;
  const int wm = wv >> 1, wn = wv & 1;

  float nrmA = 0.f, nrmB = 0.f;
  f32x4 accA[4][2], accB[4][2];
  #pragma unroll
  for (int mt = 0; mt < 4; ++mt)
    #pragma unroll
    for (int nt = 0; nt < 2; ++nt) { accA[mt][nt] = (f32x4)0.f; accB[mt][nt] = (f32x4)0.f; }

  for (int k0 = 0; k0 < KCC; k0 += 64) {
    __syncthreads();
    {
      const float4* src = (const float4*)(Abase + (size_t)ar * KCC + k0 + ahf * 32);
      float4 va[8];
      #pragma unroll
      for (int i2 = 0; i2 < 8; ++i2) va[i2] = src[i2];
      #pragma unroll
      for (int i2 = 0; i2 < 8; ++i2)
        nrmA += va[i2].x*va[i2].x + va[i2].y*va[i2].y + va[i2].z*va[i2].z + va[i2].w*va[i2].w;
      #pragma unroll
      for (int c2 = 0; c2 < 4; ++c2) {
        half8 hh, hl;
        cvt8(va[c2*2], va[c2*2+1], hh, hl);
        int cs = (ahf * 4 + c2) ^ (ar & 7);
        *(half8*)&Ahi[ar][cs * 8] = hh;
        *(half8*)&Alo[ar][cs * 8] = hl;
      }
    }
    {
      const float4* src = (const float4*)(Bbase + (size_t)brw * KCC + k0 + bq * 16);
      float4 vb[4];
      #pragma unroll
      for (int i2 = 0; i2 < 4; ++i2) vb[i2] = src[i2];
      #pragma unroll
      for (int i2 = 0; i2 < 4; ++i2)
        nrmB += vb[i2].x*vb[i2].x + vb[i2].y*vb[i2].y + vb[i2].z*vb[i2].z + vb[i2].w*vb[i2].w;
      #pragma unroll
      for (int c2 = 0; c2 < 2; ++c2) {
        half8 hh, hl;
        cvt8(vb[c2*2], vb[c2*2+1], hh, hl);
        int cs = (bq * 2 + c2) ^ (brw & 7);
        *(half8*)&Bhi[brw][cs * 8] = hh;
        *(half8*)&Blo[brw][cs * 8] = hl;
      }
    }
    __syncthreads();

    #pragma unroll
    for (int kk = 0; kk < 2; ++kk) {
      const int cs = ((kk * 4 + (l >> 4)) ^ (l & 7)) * 8;
      half8 ah[4], al[4], bh[2], bl[2];
      #pragma unroll
      for (int mt = 0; mt < 4; ++mt) {
        int row = wm * 64 + mt * 16 + (l & 15);
        ah[mt] = *(const half8*)&Ahi[row][cs];
        al[mt] = *(const half8*)&Alo[row][cs];
      }
      #pragma unroll
      for (int nt = 0; nt < 2; ++nt) {
        int row = wn * 32 + nt * 16 + (l & 15);
        bh[nt] = *(const half8*)&Bhi[row][cs];
        bl[nt] = *(const half8*)&Blo[row][cs];
      }
      #pragma unroll
      for (int mt = 0; mt < 4; ++mt)
        #pragma unroll
        for (int nt = 0; nt < 2; ++nt) {
          accA[mt][nt] = MFMA16(ah[mt], bh[nt], accA[mt][nt]);
          accB[mt][nt] = MFMA16(ah[mt], bl[nt], accB[mt][nt]);
          accB[mt][nt] = MFMA16(al[mt], bh[nt], accB[mt][nt]);
        }
    }
  }

  npA[t] = nrmA; npB[t] = nrmB;
  __syncthreads();
  if (t < 128) a2s[t] = npA[2*t] + npA[2*t + 1];
  if (t < 64)  q2s[t] = npB[4*t] + npB[4*t + 1] + npB[4*t + 2] + npB[4*t + 3];
  __syncthreads();

  #pragma unroll
  for (int nt = 0; nt < 2; ++nt) {
    float q2 = q2s[wn * 32 + nt * 16 + (l & 15)];
    float bv = 3.0e38f; int bi = 0;
    #pragma unroll
    for (int mt = 0; mt < 4; ++mt)
      #pragma unroll
      for (int r = 0; r < 4; ++r) {
        float dot = accA[mt][nt][r] + accB[mt][nt][r] * INV2K;
        int ml = wm * 64 + mt * 16 + (l >> 4) * 4 + r;
        float d = (q2 + a2s[ml]) - 2.0f * dot;
        if (d < bv) { bv = d; bi = m0 + ml; }
      }
    #pragma unroll
    for (int mm = 16; mm < 64; mm <<= 1) {
      float ov = __shfl_xor(bv, mm, 64);
      int oi = __shfl_xor(bi, mm, 64);
      if (ov < bv || (ov == bv && oi < bi)) { bv = ov; bi = oi; }
    }
    if ((l >> 4) == 0) { redv[wm][wn*32 + nt*16 + l] = bv; redi[wm][wn*32 + nt*16 + l] = bi; }
  }
  __syncthreads();
  if (t < 64) {
    float v0 = redv[0][t]; int i0 = redi[0][t];
    float v1 = redv[1][t]; int i1 = redi[1][t];
    if (v1 < v0) { v0 = v1; i0 = i1; }
    pval[((size_t)b * NCC + n0 + t) * NCHUNK + chunk] = v0;
    pidx[((size_t)b * NCC + n0 + t) * NCHUNK + chunk] = i0;
  }
}

__global__ __launch_bounds__(192) void fine_kernel(
    const float* __restrict__ f1, const float* __restrict__ fkf,
    const int* __restrict__ coarse, int* __restrict__ outf) {
  __shared__ _Float16 Qhi[16][256], Qlo[16][256];
  __shared__ float qn[16], cn[144];
  __shared__ int cROW[144];
  __shared__ int cbr[9], cbc[9];
  __shared__ float redv[3][16];
  __shared__ int   redi[3][16];

  const int t = threadIdx.x;
  const int j = blockIdx.x, i = blockIdx.y, b = blockIdx.z;
  const int l = t & 63, wv = t >> 6;

  if (t < 9) {
    int di = t / 3 - 1, dj = t % 3 - 1;
    int y = min(max(i + di, 0), HCC - 1);
    int x = min(max(j + dj, 0), WCC - 1);
    int base = ((b*HCC + y)*WCC + x) * 2;
    cbr[t] = coarse[base];
    cbc[t] = coarse[base + 1];
  }
  __syncthreads();
  if (t < 144) {
    int n9 = t >> 4, s = t & 15;
    int row = cbr[n9]*DCC + (s >> 2), col = cbc[n9]*DCC + (s & 3);
    cROW[t] = (b*HFF + row)*WFF + col;
  }
  if (t < 64) {
    int qr = l & 15, qq = l >> 4;
    int fr = i*DCC + (qr >> 2), fc = j*DCC + (qr & 3);
    const float* src = fkf + ((size_t)(b*HFF + fr)*WFF + fc) * KFF + qq * 64;
    float s2 = 0.f;
    #pragma unroll
    for (int c2 = 0; c2 < 8; ++c2) {
      float4 u0 = *(const float4*)(src + c2*8);
      float4 u1 = *(const float4*)(src + c2*8 + 4);
      s2 += u0.x*u0.x + u0.y*u0.y + u0.z*u0.z + u0.w*u0.w
          + u1.x*u1.x + u1.y*u1.y + u1.z*u1.z + u1.w*u1.w;
      half8 hh, hl;
      cvt8(u0, u1, hh, hl);
      int cs = (qq * 8 + c2) ^ (qr & 7);
      *(half8*)&Qhi[qr][cs * 8] = hh;
      *(half8*)&Qlo[qr][cs * 8] = hl;
    }
    s2 += __shfl_xor(s2, 16, 64);
    s2 += __shfl_xor(s2, 32, 64);
    if (qq == 0) qn[qr] = s2;
  }
  __syncthreads();

  const float* ap[3];
  #pragma unroll
  for (int T = 0; T < 3; ++T)
    ap[T] = f1 + (size_t)cROW[(wv*3 + T)*16 + (l & 15)] * KFF;

  f32x4 accA[3], accB[3];
  float nrmp[3];
  #pragma unroll
  for (int T = 0; T < 3; ++T) { accA[T] = (f32x4)0.f; accB[T] = (f32x4)0.f; nrmp[T] = 0.f; }

  #pragma unroll 2
  for (int s = 0; s < 8; ++s) {
    const int cs = ((s * 4 + (l >> 4)) ^ (l & 7)) * 8;
    half8 bh = *(const half8*)&Qhi[l & 15][cs];
    half8 bl = *(const half8*)&Qlo[l & 15][cs];
    #pragma unroll
    for (int T = 0; T < 3; ++T) {
      const float* p = ap[T] + s*32 + (l >> 4)*8;
      float4 u0 = *(const float4*)p;
      float4 u1 = *(const float4*)(p + 4);
      nrmp[T] += u0.x*u0.x + u0.y*u0.y + u0.z*u0.z + u0.w*u0.w
               + u1.x*u1.x + u1.y*u1.y + u1.z*u1.z + u1.w*u1.w;
      half8 ahv, alv;
      cvt8(u0, u1, ahv, alv);
      accA[T] = MFMA16(ahv, bh, accA[T]);
      accB[T] = MFMA16(ahv, bl, accB[T]);
      accB[T] = MFMA16(alv, bh, accB[T]);
    }
  }

  #pragma unroll
  for (int T = 0; T < 3; ++T) {
    float np = nrmp[T];
    np += __shfl_xor(np, 16, 64);
    np += __shfl_xor(np, 32, 64);
    if ((l >> 4) == 0) cn[(wv*3 + T)*16 + l] = np;
  }
  __syncthreads();

  {
    float q2 = qn[l & 15];
    float bv = 3.0e38f; int bi = 0;
    #pragma unroll
    for (int T = 0; T < 3; ++T)
      #pragma unroll
      for (int r = 0; r < 4; ++r) {
        float dot = accA[T][r] + accB[T][r] * INV2K;
        int m = (wv*3 + T)*16 + (l >> 4)*4 + r;
        float d = (q2 + cn[m]) - 2.0f * dot;
        if (d < bv) { bv = d; bi = m; }
      }
    #pragma unroll
    for (int mm = 16; mm < 64; mm <<= 1) {
      float ov = __shfl_xor(bv, mm, 64);
      int oi = __shfl_xor(bi, mm, 64);
      if (ov < bv || (ov == bv && oi < bi)) { bv = ov; bi = oi; }
    }
    if ((l >> 4) == 0 && l < 16) { redv[wv][l] = bv; redi[wv][l] = bi; }
  }
  __syncthreads();

  if (t < 16) {
    float v = redv[0][t]; int ix = redi[0][t];
    #pragma unroll
    for (int w = 1; w < 3; ++w) {
      float ov = redv[w][t];
      if (ov < v) { v = ov; ix = redi[w][t]; }
    }
    int n9 = ix >> 4, s3 = ix & 15;
    int br = cbr[n9]*DCC + (s3 >> 2);
    int bc = cbc[n9]*DCC + (s3 & 3);
    int fr = i*DCC + (t >> 2), fc = j*DCC + (t & 3);
    size_t ob = ((size_t)(b*HFF + fr)*WFF + fc) * 2;
    outf[ob]     = br;
    outf[ob + 1] = bc;
  }
}

extern "C" void kernel_launch(void* const* d_in, const int* in_sizes, int n_in,
                              void* d_out, int out_size, void* d_ws, size_t ws_size,
                              hipStream_t stream) {
  (void)in_sizes; (void)n_in; (void)out_size;
  const float* f1c = (const float*)d_in[0];
  const float* fkc = (const float*)d_in[1];
  const float* f1f = (const float*)d_in[2];
  const float* fkf = (const float*)d_in[3];
  int* out = (int*)d_out;

  const size_t NEED = 101220352;  // planes + norms + partials
  if (ws_size >= NEED) {
    char* w = (char*)d_ws;
    _Float16* cAhi = (_Float16*)(w);
    _Float16* cAlo = (_Float16*)(w + 8388608);
    _Float16* cBhi = (_Float16*)(w + 16777216);
    _Float16* cBlo = (_Float16*)(w + 25165824);
    _Float16* fHL  = (_Float16*)(w + 33554432);   // interleaved hi/lo, 67108864 B
    float* na_c = (float*)(w + 100663296);
    float* nq_c = (float*)(w + 100679680);
    float* na_f = (float*)(w + 100696064);
    float* pval = (float*)(w + 100958208);
    int*   pidx = (int*)  (w + 101089280);

    preconv_kernel<KCC><<<dim3(BB*NCC/4, 2), 256, 0, stream>>>(
        f1c, fkc, cAhi, cAlo, cBhi, cBlo, na_c, nq_c, BB*NCC);
    preconv_fine_kernel<<<dim3(BB*HFF*WFF/4), 256, 0, stream>>>(
        f1f, fHL, na_f, BB*HFF*WFF);
    coarse_kernel3<<<dim3(NCHUNK, NCC/64, BB), 256, 0, stream>>>(
        cAhi, cAlo, cBhi, cBlo, na_c, nq_c, pval, pidx);
    coarse_reduce_kernel<<<dim3((BB*NCC + 255)/256), 256, 0, stream>>>(pval, pidx, out);
    fine_kernel6<<<dim3(WCC/4, HCC/2, BB), 512, 0, stream>>>(
        fHL, fkf, na_f, out, out + BB*NCC*2);
  } else {
    float* pval = (float*)d_ws;
    int*   pidx = (int*)((float*)d_ws + BB*NCC*NCHUNK);
    coarse_kernel<<<dim3(NCHUNK, NCC/64, BB), 256, 0, stream>>>(f1c, fkc, pval, pidx);
    coarse_reduce_kernel<<<dim3((BB*NCC + 255)/256), 256, 0, stream>>>(pval, pidx, out);
    fine_kernel<<<dim3(WCC, HCC, BB), 192, 0, stream>>>(f1f, fkf, out, out + BB*NCC*2);
  }
}